// Round 1
// baseline (10646.415 us; speedup 1.0000x reference)
//
#include <hip/hip_runtime.h>

// ---------- constants ----------
#define Bn 2
#define Cn 256
#define Hn 128
#define Wn 128
#define HWn 16384           // 128*128
#define NCn 80
#define NPn 9

// ---------- helpers ----------
__device__ __forceinline__ float b2f(unsigned short h) {
    union { unsigned u; float f; } x; x.u = ((unsigned)h) << 16; return x.f;
}
__device__ __forceinline__ unsigned short f2bf(float f) {
    union { float f; unsigned u; } x; x.f = f;
    unsigned u = x.u + 0x7fffu + ((x.u >> 16) & 1u);   // RNE
    return (unsigned short)(u >> 16);
}
__device__ __forceinline__ float cvt(float x) { return x; }
__device__ __forceinline__ float cvt(unsigned short x) { return b2f(x); }

__device__ __forceinline__ void unp8(int4 v, float* o) {
    const unsigned* u = (const unsigned*)&v;
#pragma unroll
    for (int i = 0; i < 4; ++i) {
        union { unsigned u; float f; } a, b;
        a.u = u[i] << 16;          o[2 * i]     = a.f;
        b.u = u[i] & 0xffff0000u;  o[2 * i + 1] = b.f;
    }
}

// ---------- 3x3 conv + bias + ReLU, NCHW, bf16 out ----------
// grid: (64 tiles, 8 oc-groups, B)  block: 256 (64x4 spatial tile), OCT=32
template <typename Tin>
__global__ __launch_bounds__(256) void conv3x3(const Tin* __restrict__ in,
                                               const float* __restrict__ w,
                                               const float* __restrict__ bias,
                                               unsigned short* __restrict__ out) {
    const int tid = threadIdx.x;
    const int lx = tid & 63, ly = tid >> 6;
    const int tx = blockIdx.x & 1, ty = blockIdx.x >> 1;
    const int ox = tx * 64 + lx;
    const int oy = ty * 4 + ly;
    const int oc0 = blockIdx.y * 32;
    const int b = blockIdx.z;

    float acc[32];
#pragma unroll
    for (int o = 0; o < 32; ++o) acc[o] = bias[oc0 + o];

    const bool yv0 = (oy - 1) >= 0;
    const bool yv2 = (oy + 1) < Hn;
    const bool xv0 = ox >= 1;
    const bool xv2 = ox < (Wn - 1);

    for (int ic = 0; ic < Cn; ++ic) {
        const Tin* p = in + (((size_t)(b * Cn + ic) * Hn) + oy) * Wn + ox;
        float r[9];
        r[0] = (yv0 && xv0) ? cvt(p[-Wn - 1]) : 0.f;
        r[1] = yv0 ? cvt(p[-Wn]) : 0.f;
        r[2] = (yv0 && xv2) ? cvt(p[-Wn + 1]) : 0.f;
        r[3] = xv0 ? cvt(p[-1]) : 0.f;
        r[4] = cvt(p[0]);
        r[5] = xv2 ? cvt(p[1]) : 0.f;
        r[6] = (yv2 && xv0) ? cvt(p[Wn - 1]) : 0.f;
        r[7] = yv2 ? cvt(p[Wn]) : 0.f;
        r[8] = (yv2 && xv2) ? cvt(p[Wn + 1]) : 0.f;

        const float* wp = w + ((size_t)(oc0 * Cn + ic)) * 9;
#pragma unroll
        for (int o = 0; o < 32; ++o) {
            const float* wo = wp + (size_t)o * (Cn * 9);
            acc[o] += r[0] * wo[0] + r[1] * wo[1] + r[2] * wo[2]
                    + r[3] * wo[3] + r[4] * wo[4] + r[5] * wo[5]
                    + r[6] * wo[6] + r[7] * wo[7] + r[8] * wo[8];
        }
    }

    unsigned short* op = out + ((size_t)(b * Cn + oc0) * HWn) + oy * Wn + ox;
#pragma unroll
    for (int o = 0; o < 32; ++o) op[(size_t)o * HWn] = f2bf(fmaxf(acc[o], 0.f));
}

// ---------- 1x1 conv + bias (+optional add), fp32 out ----------
// grid: (128, OC/OCT)  block: 256
template <int OCT>
__global__ __launch_bounds__(256) void conv1x1(const unsigned short* __restrict__ in,
                                               const float* __restrict__ w,
                                               const float* __restrict__ bias,
                                               float* __restrict__ out,
                                               const float* __restrict__ add,
                                               int addStride, int OC) {
    const int hw = (blockIdx.x & 63) * 256 + threadIdx.x;
    const int b = blockIdx.x >> 6;
    const int oc0 = blockIdx.y * OCT;

    float acc[OCT];
#pragma unroll
    for (int o = 0; o < OCT; ++o) acc[o] = bias[oc0 + o];

    const unsigned short* p = in + (size_t)(b * Cn) * HWn + hw;
    for (int ic = 0; ic < Cn; ++ic) {
        float v = b2f(p[(size_t)ic * HWn]);
        const float* wp = w + (size_t)oc0 * Cn + ic;
#pragma unroll
        for (int o = 0; o < OCT; ++o) acc[o] += v * wp[(size_t)o * Cn];
    }

#pragma unroll
    for (int o = 0; o < OCT; ++o) {
        float r = acc[o];
        if (add) r += add[((size_t)(b * addStride + oc0 + o)) * HWn + hw];
        out[((size_t)(b * OC + oc0 + o)) * HWn + hw] = r;
    }
}

// ---------- NCHW -> NHWC transpose (bf16) ----------
// grid: (HW/32=512, C/32=8, B)  block 256
__global__ __launch_bounds__(256) void xposeK(const unsigned short* __restrict__ in,
                                              unsigned short* __restrict__ out) {
    __shared__ unsigned short t[32][33];
    const int b = blockIdx.z;
    const int hw0 = blockIdx.x * 32, c0 = blockIdx.y * 32;
    const int tx = threadIdx.x & 31, ty = threadIdx.x >> 5;  // ty 0..7
    const unsigned short* ip = in + (size_t)(b * Cn + c0) * HWn + hw0;
#pragma unroll
    for (int r = 0; r < 4; ++r) t[ty + 8 * r][tx] = ip[(size_t)(ty + 8 * r) * HWn + tx];
    __syncthreads();
    unsigned short* op = out + ((size_t)b * HWn + hw0) * Cn + c0;
#pragma unroll
    for (int r = 0; r < 4; ++r) op[(size_t)(ty + 8 * r) * Cn + tx] = t[tx][ty + 8 * r];
}

// ---------- DCN weight repack (O,I,3,3) -> (k,I,O) ----------
__global__ __launch_bounds__(256) void repackK(const float* __restrict__ w,
                                               float* __restrict__ o) {
    int t = blockIdx.x * 256 + threadIdx.x;   // 589824
    int oc = t & 255, ic = (t >> 8) & 255, k = t >> 16;
    o[t] = w[((size_t)(oc * Cn + ic)) * 9 + k];
}

// ---------- deformable conv (NHWC in, NCHW bf16 ReLU out) ----------
// grid: (128, 8)  block 256, OCT=32
template <bool HASMASK>
__global__ __launch_bounds__(256) void deformK(const unsigned short* __restrict__ feat, // NHWC
                                               const float* __restrict__ o27,
                                               const float* __restrict__ w2,             // [k][ic][oc]
                                               unsigned short* __restrict__ out) {
    const int hw = (blockIdx.x & 63) * 256 + threadIdx.x;
    const int b = blockIdx.x >> 6;
    const int oc0 = blockIdx.y * 32;
    const int y = hw >> 7, x = hw & 127;

    int cidx[9][4];
    float cw[9][4];
    const float* ob = o27 + (size_t)(b * 27) * HWn + hw;
#pragma unroll
    for (int k = 0; k < 9; ++k) {
        const int ky = k / 3, kx = k % 3;
        float offy = ob[(size_t)(2 * k) * HWn];
        float offx = ob[(size_t)(2 * k + 1) * HWn];
        float py = (float)(y + ky - 1) + offy;
        float px = (float)(x + kx - 1) + offx;
        float y0f = floorf(py), x0f = floorf(px);
        float wy1 = py - y0f, wx1 = px - x0f;
        int y0 = (int)y0f, x0 = (int)x0f;
        int y1 = y0 + 1, x1 = x0 + 1;
        float m = 1.f;
        if (HASMASK) m = ob[(size_t)(18 + k) * HWn];
        float w00 = (1.f - wy1) * (1.f - wx1) * m;
        float w01 = (1.f - wy1) * wx1 * m;
        float w10 = wy1 * (1.f - wx1) * m;
        float w11 = wy1 * wx1 * m;
        bool vy0 = (y0 >= 0) && (y0 < Hn), vy1 = (y1 >= 0) && (y1 < Hn);
        bool vx0 = (x0 >= 0) && (x0 < Wn), vx1 = (x1 >= 0) && (x1 < Wn);
        int yc0 = min(max(y0, 0), Hn - 1), yc1 = min(max(y1, 0), Hn - 1);
        int xc0 = min(max(x0, 0), Wn - 1), xc1 = min(max(x1, 0), Wn - 1);
        cidx[k][0] = (yc0 * Wn + xc0) * Cn; cw[k][0] = (vy0 && vx0) ? w00 : 0.f;
        cidx[k][1] = (yc0 * Wn + xc1) * Cn; cw[k][1] = (vy0 && vx1) ? w01 : 0.f;
        cidx[k][2] = (yc1 * Wn + xc0) * Cn; cw[k][2] = (vy1 && vx0) ? w10 : 0.f;
        cidx[k][3] = (yc1 * Wn + xc1) * Cn; cw[k][3] = (vy1 && vx1) ? w11 : 0.f;
    }

    const unsigned short* fb = feat + (size_t)b * HWn * Cn;
    float acc[32];
#pragma unroll
    for (int o = 0; o < 32; ++o) acc[o] = 0.f;

    for (int ic0 = 0; ic0 < Cn; ic0 += 8) {
#pragma unroll
        for (int k = 0; k < 9; ++k) {
            int4 A  = *(const int4*)(fb + cidx[k][0] + ic0);
            int4 Bc = *(const int4*)(fb + cidx[k][1] + ic0);
            int4 Cc = *(const int4*)(fb + cidx[k][2] + ic0);
            int4 Dc = *(const int4*)(fb + cidx[k][3] + ic0);
            float fa[8], fbv[8], fc[8], fd[8], va[8];
            unp8(A, fa); unp8(Bc, fbv); unp8(Cc, fc); unp8(Dc, fd);
#pragma unroll
            for (int j = 0; j < 8; ++j)
                va[j] = cw[k][0] * fa[j] + cw[k][1] * fbv[j] + cw[k][2] * fc[j] + cw[k][3] * fd[j];
            const float* wr = w2 + ((size_t)(k * Cn + ic0)) * Cn + oc0;
#pragma unroll
            for (int j = 0; j < 8; ++j) {
#pragma unroll
                for (int o = 0; o < 32; ++o) acc[o] += va[j] * wr[(size_t)j * Cn + o];
            }
        }
    }

    unsigned short* op = out + ((size_t)(b * Cn + oc0)) * HWn + hw;
#pragma unroll
    for (int o = 0; o < 32; ++o) op[(size_t)o * HWn] = f2bf(fmaxf(acc[o], 0.f));
}

// ---------- postproc: wh + reg from refined points ----------
// grid 128, block 256
__global__ __launch_bounds__(256) void postK(const float* __restrict__ r18,
                                             float* __restrict__ wh,
                                             float* __restrict__ reg) {
    const int hw = (blockIdx.x & 63) * 256 + threadIdx.x;
    const int b = blockIdx.x >> 6;
    const float* p = r18 + (size_t)(b * 18) * HWn + hw;
    float v[18];
#pragma unroll
    for (int c = 0; c < 18; ++c) v[c] = p[(size_t)c * HWn];
    float s0 = 0.f, s1 = 0.f;
#pragma unroll
    for (int q = 0; q < 9; ++q) { s0 += v[2 * q]; s1 += v[2 * q + 1]; }
    float m0 = s0 * (1.f / 9.f), m1 = s1 * (1.f / 9.f);
    float w0 = 0.f, w1 = 0.f;
#pragma unroll
    for (int q = 0; q < 9; ++q) {
        w0 = fmaxf(w0, fabsf(v[2 * q] + m0));
        w1 = fmaxf(w1, fabsf(v[2 * q + 1] + m1));
    }
    wh[(size_t)(b * 2 + 0) * HWn + hw] = w0;
    wh[(size_t)(b * 2 + 1) * HWn + hw] = w1;
    reg[(size_t)(b * 2 + 0) * HWn + hw] = m0;
    reg[(size_t)(b * 2 + 1) * HWn + hw] = m1;
}

// ---------- host ----------
extern "C" void kernel_launch(void* const* d_in, const int* in_sizes, int n_in,
                              void* d_out, int out_size, void* d_ws, size_t ws_size,
                              hipStream_t stream) {
    const float* x          = (const float*)d_in[0];
    const float* cls_w0     = (const float*)d_in[1];
    const float* cls_b0     = (const float*)d_in[2];
    const float* reg_w0     = (const float*)d_in[3];
    const float* reg_b0     = (const float*)d_in[4];
    const float* cls_w1     = (const float*)d_in[5];
    const float* cls_b1     = (const float*)d_in[6];
    const float* reg_w1     = (const float*)d_in[7];
    const float* reg_b1     = (const float*)d_in[8];
    const float* cls_w2     = (const float*)d_in[9];
    const float* cls_b2     = (const float*)d_in[10];
    const float* reg_w2     = (const float*)d_in[11];
    const float* reg_b2     = (const float*)d_in[12];
    const float* init_conv_w = (const float*)d_in[13];
    const float* init_conv_b = (const float*)d_in[14];
    const float* init_out_w  = (const float*)d_in[15];
    const float* init_out_b  = (const float*)d_in[16];
    const float* dcn_cls_w   = (const float*)d_in[17];
    const float* cls_out_w   = (const float*)d_in[18];
    const float* cls_out_b   = (const float*)d_in[19];
    const float* dcn_ref_w   = (const float*)d_in[20];
    const float* ref_out_w   = (const float*)d_in[21];
    const float* ref_out_b   = (const float*)d_in[22];

    float* out = (float*)d_out;

    char* ws = (char*)d_ws;
    const size_t IMG = (size_t)Bn * Cn * HWn * sizeof(unsigned short);  // 16 MiB
    unsigned short* bufA  = (unsigned short*)ws;           ws += IMG;
    unsigned short* bufB  = (unsigned short*)ws;           ws += IMG;
    unsigned short* bufC  = (unsigned short*)ws;           ws += IMG;   // cls_feat
    unsigned short* bufV  = (unsigned short*)ws;           ws += IMG;   // NHWC staging
    float* O27 = (float*)ws;  ws += (size_t)Bn * 27 * HWn * sizeof(float);
    float* R18 = (float*)ws;  ws += (size_t)Bn * 18 * HWn * sizeof(float);
    float* W2A = (float*)ws;  ws += (size_t)9 * Cn * Cn * sizeof(float);
    float* W2B = (float*)ws;  ws += (size_t)9 * Cn * Cn * sizeof(float);

    const dim3 blk(256);
    const dim3 cgrd(64, 8, Bn);      // conv3x3
    const dim3 tgrd(512, 8, Bn);     // transpose
    const dim3 dgrd(128, 8);         // deform

    // DCN weight repacks
    repackK<<<2304, blk, 0, stream>>>(dcn_cls_w, W2A);
    repackK<<<2304, blk, 0, stream>>>(dcn_ref_w, W2B);

    // cls tower
    conv3x3<float><<<cgrd, blk, 0, stream>>>(x, cls_w0, cls_b0, bufA);
    conv3x3<unsigned short><<<cgrd, blk, 0, stream>>>(bufA, cls_w1, cls_b1, bufB);
    conv3x3<unsigned short><<<cgrd, blk, 0, stream>>>(bufB, cls_w2, cls_b2, bufC);

    // reg tower -> pts_feat in bufA
    conv3x3<float><<<cgrd, blk, 0, stream>>>(x, reg_w0, reg_b0, bufA);
    conv3x3<unsigned short><<<cgrd, blk, 0, stream>>>(bufA, reg_w1, reg_b1, bufB);
    conv3x3<unsigned short><<<cgrd, blk, 0, stream>>>(bufB, reg_w2, reg_b2, bufA);

    // init head: conv3x3(relu) -> 1x1 (27ch)
    conv3x3<unsigned short><<<cgrd, blk, 0, stream>>>(bufA, init_conv_w, init_conv_b, bufB);
    conv1x1<27><<<dim3(128, 1), blk, 0, stream>>>(bufB, init_out_w, init_out_b, O27, nullptr, 0, 27);

    // cls branch: deform(cls_feat, mask) -> relu -> 1x1 (80ch) -> d_out
    xposeK<<<tgrd, blk, 0, stream>>>(bufC, bufV);
    deformK<true><<<dgrd, blk, 0, stream>>>(bufV, O27, W2A, bufB);
    conv1x1<16><<<dim3(128, 5), blk, 0, stream>>>(bufB, cls_out_w, cls_out_b, out, nullptr, 0, NCn);

    // refine branch: deform(pts_feat) -> relu -> 1x1 (18ch) + offset -> R18
    xposeK<<<tgrd, blk, 0, stream>>>(bufA, bufV);
    deformK<false><<<dgrd, blk, 0, stream>>>(bufV, O27, W2B, bufB);
    conv1x1<18><<<dim3(128, 1), blk, 0, stream>>>(bufB, ref_out_w, ref_out_b, R18, O27, 27, 18);

    // wh / reg
    postK<<<128, blk, 0, stream>>>(R18, out + (size_t)Bn * NCn * HWn,
                                   out + (size_t)Bn * NCn * HWn + (size_t)Bn * 2 * HWn);
}

// Round 2
// 1200.116 us; speedup vs baseline: 8.8712x; 8.8712x over previous
//
#include <hip/hip_runtime.h>

#define Bn 2
#define Cn 256
#define Hn 128
#define Wn 128
#define HWn 16384
#define NCn 80

typedef __attribute__((ext_vector_type(4))) float f32x4;
typedef __attribute__((ext_vector_type(8))) short bf16x8;

__device__ __forceinline__ float b2f(unsigned short h) {
    union { unsigned u; float f; } x; x.u = ((unsigned)h) << 16; return x.f;
}
__device__ __forceinline__ unsigned short f2bf(float f) {
    union { float f; unsigned u; } x; x.f = f;
    unsigned u = x.u + 0x7fffu + ((x.u >> 16) & 1u);   // RNE
    return (unsigned short)(u >> 16);
}
__device__ __forceinline__ void unp8(int4 v, float* o) {
    const unsigned* u = (const unsigned*)&v;
#pragma unroll
    for (int i = 0; i < 4; ++i) {
        union { unsigned u; float f; } a, b;
        a.u = u[i] << 16;          o[2 * i]     = a.f;
        b.u = u[i] & 0xffff0000u;  o[2 * i + 1] = b.f;
    }
}

// async global->LDS, 16B per lane, wave-uniform LDS base + lane*16
#define GLOAD16(gp, lp) __builtin_amdgcn_global_load_lds( \
    (__attribute__((address_space(1))) unsigned int*)(gp), \
    (__attribute__((address_space(3))) unsigned int*)(lp), 16, 0, 0)

// ---------- zero scratch ----------
__global__ void zeroK(unsigned short* z) { z[threadIdx.x] = 0; }

// ---------- x (NCHW f32) -> NHWC bf16 ----------
__global__ __launch_bounds__(256) void xinK(const float* __restrict__ x,
                                            unsigned short* __restrict__ o) {
    __shared__ float tb[32][33];
    const int b = blockIdx.z;
    const int hw0 = blockIdx.x * 32, c0 = blockIdx.y * 32;
    const int tx = threadIdx.x & 31, ty = threadIdx.x >> 5;
    const float* ip = x + ((size_t)(b * Cn + c0)) * HWn + hw0;
#pragma unroll
    for (int r = 0; r < 4; ++r) tb[ty + 8 * r][tx] = ip[(size_t)(ty + 8 * r) * HWn + tx];
    __syncthreads();
    unsigned short* op = o + ((size_t)(b * HWn + hw0)) * Cn + c0;
#pragma unroll
    for (int r = 0; r < 4; ++r) op[(size_t)(ty + 8 * r) * Cn + tx] = f2bf(tb[tx][ty + 8 * r]);
}

// ---------- weight repack (O,I,3,3) f32 -> [k][oc][ic] bf16 ----------
__global__ __launch_bounds__(256) void repack3(const float* __restrict__ w,
                                               unsigned short* __restrict__ o) {
    int t = blockIdx.x * 256 + threadIdx.x;          // < 589824
    int ic = t & 255, oc = (t >> 8) & 255, k = t >> 16;
    o[t] = f2bf(w[((size_t)(oc * Cn + ic)) * 9 + k]);
}

// ---------- implicit-GEMM 3x3 conv, NHWC bf16 -> NHWC bf16, bias+ReLU ----------
// grid (B*H=256, 2), block 256 (4 waves, 2 oc x 2 px), tile 128oc x 128px, BK=64
__global__ __launch_bounds__(256, 2) void convGemm(const unsigned short* __restrict__ feat,
                                                   const unsigned short* __restrict__ Wp,
                                                   const float* __restrict__ bias,
                                                   const unsigned short* __restrict__ zb,
                                                   unsigned short* __restrict__ out) {
    __shared__ __align__(16) unsigned short lA[128 * 64];   // weights [oc][ic]
    __shared__ __align__(16) unsigned short lB[128 * 64];   // feat [px][ic]
    const int tid = threadIdx.x;
    const int l = tid & 63, w = tid >> 6;
    const int w_oc = w & 1, w_px = w >> 1;
    const int ry = blockIdx.x;                    // b*H + y
    const int b = ry >> 7, y = ry & 127;
    const int oc0 = blockIdx.y * 128;
    const int lr = l & 15, lg = l >> 4;

    int rI[4], cI[4], dI[4];
#pragma unroll
    for (int i = 0; i < 4; ++i) {
        int ps = (i * 4 + w) * 64 + l;            // physical 16B slot
        rI[i] = ps >> 3;
        cI[i] = ((ps & 7) ^ (rI[i] & 7)) * 8;     // logical chunk -> elem offset
        dI[i] = (i * 4 + w) * 512;                // LDS elem base (wave-uniform)
    }

    f32x4 acc[4][4];
#pragma unroll
    for (int i = 0; i < 4; ++i)
#pragma unroll
        for (int j = 0; j < 4; ++j) acc[i][j] = (f32x4){0.f, 0.f, 0.f, 0.f};

#pragma unroll 1
    for (int k = 0; k < 9; ++k) {
        const int dy = k / 3 - 1, dx = k % 3 - 1;
        const int yy = y + dy;
        const bool vy = (unsigned)yy < (unsigned)Hn;
        const size_t fbase = ((size_t)(b * Hn + yy)) * Wn;
#pragma unroll 1
        for (int cc = 0; cc < 4; ++cc) {
            const int c0 = cc * 64;
            const unsigned short* wk = Wp + (size_t)k * 65536 + (size_t)oc0 * Cn + c0;
#pragma unroll
            for (int i = 0; i < 4; ++i)
                GLOAD16(wk + rI[i] * Cn + cI[i], &lA[dI[i]]);
#pragma unroll
            for (int i = 0; i < 4; ++i) {
                const int pxs = rI[i] + dx;
                const unsigned short* g = (vy && (unsigned)pxs < (unsigned)Wn)
                    ? feat + ((fbase + pxs) * Cn + c0 + cI[i])
                    : zb;
                GLOAD16(g, &lB[dI[i]]);
            }
            __syncthreads();
#pragma unroll
            for (int h = 0; h < 2; ++h) {
                bf16x8 av[4], bv[4];
#pragma unroll
                for (int fm = 0; fm < 4; ++fm) {
                    const int row = w_oc * 64 + fm * 16 + lr;
                    const int ch = h * 4 + lg;
                    av[fm] = *(const bf16x8*)&lA[row * 64 + ((ch ^ (row & 7)) * 8)];
                }
#pragma unroll
                for (int fn = 0; fn < 4; ++fn) {
                    const int row = w_px * 64 + fn * 16 + lr;
                    const int ch = h * 4 + lg;
                    bv[fn] = *(const bf16x8*)&lB[row * 64 + ((ch ^ (row & 7)) * 8)];
                }
#pragma unroll
                for (int fm = 0; fm < 4; ++fm)
#pragma unroll
                    for (int fn = 0; fn < 4; ++fn)
                        acc[fm][fn] = __builtin_amdgcn_mfma_f32_16x16x32_bf16(
                            av[fm], bv[fn], acc[fm][fn], 0, 0, 0);
            }
            __syncthreads();
        }
    }

#pragma unroll
    for (int fm = 0; fm < 4; ++fm) {
        const int ocb = oc0 + w_oc * 64 + fm * 16 + lg * 4;
        const float b0 = bias[ocb], b1 = bias[ocb + 1], b2 = bias[ocb + 2], b3 = bias[ocb + 3];
#pragma unroll
        for (int fn = 0; fn < 4; ++fn) {
            const int px = w_px * 64 + fn * 16 + lr;
            f32x4 v = acc[fm][fn];
            unsigned u0 = (unsigned)f2bf(fmaxf(v[0] + b0, 0.f)) | ((unsigned)f2bf(fmaxf(v[1] + b1, 0.f)) << 16);
            unsigned u1 = (unsigned)f2bf(fmaxf(v[2] + b2, 0.f)) | ((unsigned)f2bf(fmaxf(v[3] + b3, 0.f)) << 16);
            uint2 st; st.x = u0; st.y = u1;
            *(uint2*)&out[((size_t)ry * Wn + px) * Cn + ocb] = st;
        }
    }
}

// ---------- deformable conv as sampled implicit GEMM ----------
// grid (256), block 512 (8 waves, 4 oc x 2 px), tile 256oc x 128px, BK=64, ReLU out
template <bool HASMASK>
__global__ __launch_bounds__(512, 2) void dcnGemm(const unsigned short* __restrict__ feat, // NHWC bf16
                                                  const float* __restrict__ o27,           // NCHW f32
                                                  const unsigned short* __restrict__ Wp,   // [k][oc][ic] bf16
                                                  unsigned short* __restrict__ out) {
    __shared__ __align__(16) unsigned short lA[256 * 64];
    __shared__ __align__(16) unsigned short lB[128 * 64];
    const int tid = threadIdx.x;
    const int l = tid & 63, w = tid >> 6;
    const int w_oc = w & 3, w_px = w >> 2;
    const int ry = blockIdx.x;
    const int b = ry >> 7, y = ry & 127;
    const int lr = l & 15, lg = l >> 4;

    int rI[4], cI[4], dI[4];
#pragma unroll
    for (int i = 0; i < 4; ++i) {
        int ps = (i * 8 + w) * 64 + l;
        rI[i] = ps >> 3;
        cI[i] = ((ps & 7) ^ (rI[i] & 7)) * 8;
        dI[i] = (i * 8 + w) * 512;
    }

    const int sp = tid >> 2;            // sampled pixel 0..127
    const int pc0 = (tid & 3) * 2;      // physical chunk pair

    f32x4 acc[4][4];
#pragma unroll
    for (int i = 0; i < 4; ++i)
#pragma unroll
        for (int j = 0; j < 4; ++j) acc[i][j] = (f32x4){0.f, 0.f, 0.f, 0.f};

    const unsigned short* fb = feat + (size_t)b * HWn * Cn;
    const float* ob = o27 + (size_t)b * 27 * HWn + y * Wn + sp;

#pragma unroll 1
    for (int k = 0; k < 9; ++k) {
        // bilinear params for (sp, k)
        const float offy = ob[(size_t)(2 * k) * HWn];
        const float offx = ob[(size_t)(2 * k + 1) * HWn];
        const float m = HASMASK ? ob[(size_t)(18 + k) * HWn] : 1.f;
        const float py = (float)(y + k / 3 - 1) + offy;
        const float px = (float)(sp + k % 3 - 1) + offx;
        const float y0f = floorf(py), x0f = floorf(px);
        const float wy1 = py - y0f, wx1 = px - x0f;
        const int iy0 = (int)y0f, ix0 = (int)x0f;
        const int iy1 = iy0 + 1, ix1 = ix0 + 1;
        const bool vy0 = (unsigned)iy0 < (unsigned)Hn, vy1 = (unsigned)iy1 < (unsigned)Hn;
        const bool vx0 = (unsigned)ix0 < (unsigned)Wn, vx1 = (unsigned)ix1 < (unsigned)Wn;
        const int yc0 = min(max(iy0, 0), Hn - 1), yc1 = min(max(iy1, 0), Hn - 1);
        const int xc0 = min(max(ix0, 0), Wn - 1), xc1 = min(max(ix1, 0), Wn - 1);
        const float cw0 = (vy0 && vx0) ? (1.f - wy1) * (1.f - wx1) * m : 0.f;
        const float cw1 = (vy0 && vx1) ? (1.f - wy1) * wx1 * m : 0.f;
        const float cw2 = (vy1 && vx0) ? wy1 * (1.f - wx1) * m : 0.f;
        const float cw3 = (vy1 && vx1) ? wy1 * wx1 * m : 0.f;
        const int ci0 = (yc0 * Wn + xc0) * Cn;
        const int ci1 = (yc0 * Wn + xc1) * Cn;
        const int ci2 = (yc1 * Wn + xc0) * Cn;
        const int ci3 = (yc1 * Wn + xc1) * Cn;

#pragma unroll 1
        for (int cc = 0; cc < 4; ++cc) {
            const int c0 = cc * 64;
            const unsigned short* wk = Wp + (size_t)k * 65536 + c0;
#pragma unroll
            for (int i = 0; i < 4; ++i)
                GLOAD16(wk + rI[i] * Cn + cI[i], &lA[dI[i]]);
            // sampled feat tile: 2 slots per thread, reg-staged ds_write
#pragma unroll
            for (int s = 0; s < 2; ++s) {
                const int pcS = pc0 + s;
                const int cb = c0 + ((pcS ^ (sp & 7)) * 8);
                int4 q0 = *(const int4*)(fb + ci0 + cb);
                int4 q1 = *(const int4*)(fb + ci1 + cb);
                int4 q2 = *(const int4*)(fb + ci2 + cb);
                int4 q3 = *(const int4*)(fb + ci3 + cb);
                float f0[8], f1[8], f2[8], f3[8];
                unp8(q0, f0); unp8(q1, f1); unp8(q2, f2); unp8(q3, f3);
                unsigned u[4];
#pragma unroll
                for (int jj = 0; jj < 4; ++jj) {
                    float e0 = cw0 * f0[2 * jj] + cw1 * f1[2 * jj] + cw2 * f2[2 * jj] + cw3 * f3[2 * jj];
                    float e1 = cw0 * f0[2 * jj + 1] + cw1 * f1[2 * jj + 1] + cw2 * f2[2 * jj + 1] + cw3 * f3[2 * jj + 1];
                    u[jj] = (unsigned)f2bf(e0) | ((unsigned)f2bf(e1) << 16);
                }
                int4 pk; pk.x = u[0]; pk.y = u[1]; pk.z = u[2]; pk.w = u[3];
                *(int4*)&lB[sp * 64 + pcS * 8] = pk;
            }
            __syncthreads();
#pragma unroll
            for (int h = 0; h < 2; ++h) {
                bf16x8 av[4], bv[4];
#pragma unroll
                for (int fm = 0; fm < 4; ++fm) {
                    const int row = w_oc * 64 + fm * 16 + lr;
                    const int ch = h * 4 + lg;
                    av[fm] = *(const bf16x8*)&lA[row * 64 + ((ch ^ (row & 7)) * 8)];
                }
#pragma unroll
                for (int fn = 0; fn < 4; ++fn) {
                    const int row = w_px * 64 + fn * 16 + lr;
                    const int ch = h * 4 + lg;
                    bv[fn] = *(const bf16x8*)&lB[row * 64 + ((ch ^ (row & 7)) * 8)];
                }
#pragma unroll
                for (int fm = 0; fm < 4; ++fm)
#pragma unroll
                    for (int fn = 0; fn < 4; ++fn)
                        acc[fm][fn] = __builtin_amdgcn_mfma_f32_16x16x32_bf16(
                            av[fm], bv[fn], acc[fm][fn], 0, 0, 0);
            }
            __syncthreads();
        }
    }

#pragma unroll
    for (int fm = 0; fm < 4; ++fm) {
        const int ocb = w_oc * 64 + fm * 16 + lg * 4;
#pragma unroll
        for (int fn = 0; fn < 4; ++fn) {
            const int px = w_px * 64 + fn * 16 + lr;
            f32x4 v = acc[fm][fn];
            unsigned u0 = (unsigned)f2bf(fmaxf(v[0], 0.f)) | ((unsigned)f2bf(fmaxf(v[1], 0.f)) << 16);
            unsigned u1 = (unsigned)f2bf(fmaxf(v[2], 0.f)) | ((unsigned)f2bf(fmaxf(v[3], 0.f)) << 16);
            uint2 st; st.x = u0; st.y = u1;
            *(uint2*)&out[((size_t)ry * Wn + px) * Cn + ocb] = st;
        }
    }
}

// ---------- 1x1 head, NHWC bf16 in, NCHW f32 out (+optional add) ----------
template <int N>
__global__ __launch_bounds__(256) void head1x1(const unsigned short* __restrict__ feat,
                                               const float* __restrict__ w,
                                               const float* __restrict__ bias,
                                               float* __restrict__ out,
                                               const float* __restrict__ add,
                                               int addC) {
    const int t = blockIdx.x * 256 + threadIdx.x;   // 0..32767
    const int b = t >> 14, hw = t & 16383;
    float acc[N];
#pragma unroll
    for (int o = 0; o < N; ++o) acc[o] = bias[o];
    const unsigned short* p = feat + (size_t)t * Cn;
    for (int ic0 = 0; ic0 < Cn; ic0 += 8) {
        int4 v = *(const int4*)(p + ic0);
        float f[8];
        unp8(v, f);
#pragma unroll
        for (int j = 0; j < 8; ++j)
#pragma unroll
            for (int o = 0; o < N; ++o) acc[o] += f[j] * w[o * Cn + ic0 + j];
    }
#pragma unroll
    for (int o = 0; o < N; ++o) {
        float r = acc[o];
        if (add) r += add[((size_t)(b * addC + o)) * HWn + hw];
        out[((size_t)(b * N + o)) * HWn + hw] = r;
    }
}

// ---------- postproc ----------
__global__ __launch_bounds__(256) void postK(const float* __restrict__ r18,
                                             float* __restrict__ wh,
                                             float* __restrict__ reg) {
    const int hw = (blockIdx.x & 63) * 256 + threadIdx.x;
    const int b = blockIdx.x >> 6;
    const float* p = r18 + (size_t)(b * 18) * HWn + hw;
    float v[18];
#pragma unroll
    for (int c = 0; c < 18; ++c) v[c] = p[(size_t)c * HWn];
    float s0 = 0.f, s1 = 0.f;
#pragma unroll
    for (int q = 0; q < 9; ++q) { s0 += v[2 * q]; s1 += v[2 * q + 1]; }
    float m0 = s0 * (1.f / 9.f), m1 = s1 * (1.f / 9.f);
    float w0 = 0.f, w1 = 0.f;
#pragma unroll
    for (int q = 0; q < 9; ++q) {
        w0 = fmaxf(w0, fabsf(v[2 * q] + m0));
        w1 = fmaxf(w1, fabsf(v[2 * q + 1] + m1));
    }
    wh[(size_t)(b * 2 + 0) * HWn + hw] = w0;
    wh[(size_t)(b * 2 + 1) * HWn + hw] = w1;
    reg[(size_t)(b * 2 + 0) * HWn + hw] = m0;
    reg[(size_t)(b * 2 + 1) * HWn + hw] = m1;
}

// ---------- host ----------
extern "C" void kernel_launch(void* const* d_in, const int* in_sizes, int n_in,
                              void* d_out, int out_size, void* d_ws, size_t ws_size,
                              hipStream_t stream) {
    const float* x           = (const float*)d_in[0];
    const float* cls_w0      = (const float*)d_in[1];
    const float* cls_b0      = (const float*)d_in[2];
    const float* reg_w0      = (const float*)d_in[3];
    const float* reg_b0      = (const float*)d_in[4];
    const float* cls_w1      = (const float*)d_in[5];
    const float* cls_b1      = (const float*)d_in[6];
    const float* reg_w1      = (const float*)d_in[7];
    const float* reg_b1      = (const float*)d_in[8];
    const float* cls_w2      = (const float*)d_in[9];
    const float* cls_b2      = (const float*)d_in[10];
    const float* reg_w2      = (const float*)d_in[11];
    const float* reg_b2      = (const float*)d_in[12];
    const float* init_conv_w = (const float*)d_in[13];
    const float* init_conv_b = (const float*)d_in[14];
    const float* init_out_w  = (const float*)d_in[15];
    const float* init_out_b  = (const float*)d_in[16];
    const float* dcn_cls_w   = (const float*)d_in[17];
    const float* cls_out_w   = (const float*)d_in[18];
    const float* cls_out_b   = (const float*)d_in[19];
    const float* dcn_ref_w   = (const float*)d_in[20];
    const float* ref_out_w   = (const float*)d_in[21];
    const float* ref_out_b   = (const float*)d_in[22];

    float* out = (float*)d_out;

    char* ws = (char*)d_ws;
    const size_t IMG = (size_t)Bn * HWn * Cn * sizeof(unsigned short);  // 16 MiB
    unsigned short* Xb  = (unsigned short*)ws; ws += IMG;
    unsigned short* T1  = (unsigned short*)ws; ws += IMG;
    unsigned short* T2  = (unsigned short*)ws; ws += IMG;
    unsigned short* CLS = (unsigned short*)ws; ws += IMG;
    unsigned short* PTS = (unsigned short*)ws; ws += IMG;
    float* O27 = (float*)ws; ws += (size_t)Bn * 27 * HWn * sizeof(float);
    float* R18 = (float*)ws; ws += (size_t)Bn * 18 * HWn * sizeof(float);
    const size_t WSZ = (size_t)9 * Cn * Cn;   // 589824 elems per weight
    unsigned short* Wpk = (unsigned short*)ws; ws += 9 * WSZ * sizeof(unsigned short);
    unsigned short* ZB = (unsigned short*)ws;  ws += 512;

    unsigned short* W_cls0 = Wpk + 0 * WSZ;
    unsigned short* W_cls1 = Wpk + 1 * WSZ;
    unsigned short* W_cls2 = Wpk + 2 * WSZ;
    unsigned short* W_reg0 = Wpk + 3 * WSZ;
    unsigned short* W_reg1 = Wpk + 4 * WSZ;
    unsigned short* W_reg2 = Wpk + 5 * WSZ;
    unsigned short* W_init = Wpk + 6 * WSZ;
    unsigned short* W_dcls = Wpk + 7 * WSZ;
    unsigned short* W_dref = Wpk + 8 * WSZ;

    const dim3 blk(256);
    const dim3 cgrd(256, 2);
    const dim3 xgrd(512, 8, Bn);

    zeroK<<<1, 128, 0, stream>>>(ZB);
    repack3<<<2304, blk, 0, stream>>>(cls_w0, W_cls0);
    repack3<<<2304, blk, 0, stream>>>(cls_w1, W_cls1);
    repack3<<<2304, blk, 0, stream>>>(cls_w2, W_cls2);
    repack3<<<2304, blk, 0, stream>>>(reg_w0, W_reg0);
    repack3<<<2304, blk, 0, stream>>>(reg_w1, W_reg1);
    repack3<<<2304, blk, 0, stream>>>(reg_w2, W_reg2);
    repack3<<<2304, blk, 0, stream>>>(init_conv_w, W_init);
    repack3<<<2304, blk, 0, stream>>>(dcn_cls_w, W_dcls);
    repack3<<<2304, blk, 0, stream>>>(dcn_ref_w, W_dref);
    xinK<<<xgrd, blk, 0, stream>>>(x, Xb);

    // cls tower
    convGemm<<<cgrd, blk, 0, stream>>>(Xb, W_cls0, cls_b0, ZB, T1);
    convGemm<<<cgrd, blk, 0, stream>>>(T1, W_cls1, cls_b1, ZB, T2);
    convGemm<<<cgrd, blk, 0, stream>>>(T2, W_cls2, cls_b2, ZB, CLS);
    // reg tower
    convGemm<<<cgrd, blk, 0, stream>>>(Xb, W_reg0, reg_b0, ZB, T1);
    convGemm<<<cgrd, blk, 0, stream>>>(T1, W_reg1, reg_b1, ZB, T2);
    convGemm<<<cgrd, blk, 0, stream>>>(T2, W_reg2, reg_b2, ZB, PTS);
    // init head
    convGemm<<<cgrd, blk, 0, stream>>>(PTS, W_init, init_conv_b, ZB, T1);
    head1x1<27><<<128, blk, 0, stream>>>(T1, init_out_w, init_out_b, O27, nullptr, 0);
    // cls branch
    dcnGemm<true><<<256, dim3(512), 0, stream>>>(CLS, O27, W_dcls, T2);
    head1x1<NCn><<<128, blk, 0, stream>>>(T2, cls_out_w, cls_out_b, out, nullptr, 0);
    // refine branch
    dcnGemm<false><<<256, dim3(512), 0, stream>>>(PTS, O27, W_dref, T1);
    head1x1<18><<<128, blk, 0, stream>>>(T1, ref_out_w, ref_out_b, R18, O27, 27);

    postK<<<128, blk, 0, stream>>>(R18,
                                   out + (size_t)Bn * NCn * HWn,
                                   out + (size_t)Bn * NCn * HWn + (size_t)Bn * 2 * HWn);
}

// Round 3
// 658.095 us; speedup vs baseline: 16.1776x; 1.8236x over previous
//
#include <hip/hip_runtime.h>

#define Bn 2
#define Cn 256
#define Hn 128
#define Wn 128
#define HWn 16384
#define NCn 80

typedef __attribute__((ext_vector_type(4))) float f32x4;
typedef __attribute__((ext_vector_type(8))) short bf16x8;

__device__ __forceinline__ float b2f(unsigned short h) {
    union { unsigned u; float f; } x; x.u = ((unsigned)h) << 16; return x.f;
}
__device__ __forceinline__ unsigned short f2bf(float f) {
    union { float f; unsigned u; } x; x.f = f;
    unsigned u = x.u + 0x7fffu + ((x.u >> 16) & 1u);   // RNE
    return (unsigned short)(u >> 16);
}
__device__ __forceinline__ void unp8(int4 v, float* o) {
    const unsigned* u = (const unsigned*)&v;
#pragma unroll
    for (int i = 0; i < 4; ++i) {
        union { unsigned u; float f; } a, b;
        a.u = u[i] << 16;          o[2 * i]     = a.f;
        b.u = u[i] & 0xffff0000u;  o[2 * i + 1] = b.f;
    }
}

// async global->LDS, 16B per lane, wave-uniform LDS base + lane*16
#define GLOAD16(gp, lp) __builtin_amdgcn_global_load_lds( \
    (__attribute__((address_space(1))) unsigned int*)(gp), \
    (__attribute__((address_space(3))) unsigned int*)(lp), 16, 0, 0)

// ---------- zero scratch ----------
__global__ void zeroK(unsigned short* z) { z[threadIdx.x] = 0; }

// ---------- x (NCHW f32) -> NHWC bf16 ----------
__global__ __launch_bounds__(256) void xinK(const float* __restrict__ x,
                                            unsigned short* __restrict__ o) {
    __shared__ float tb[32][33];
    const int b = blockIdx.z;
    const int hw0 = blockIdx.x * 32, c0 = blockIdx.y * 32;
    const int tx = threadIdx.x & 31, ty = threadIdx.x >> 5;
    const float* ip = x + ((size_t)(b * Cn + c0)) * HWn + hw0;
#pragma unroll
    for (int r = 0; r < 4; ++r) tb[ty + 8 * r][tx] = ip[(size_t)(ty + 8 * r) * HWn + tx];
    __syncthreads();
    unsigned short* op = o + ((size_t)(b * HWn + hw0)) * Cn + c0;
#pragma unroll
    for (int r = 0; r < 4; ++r) op[(size_t)(ty + 8 * r) * Cn + tx] = f2bf(tb[tx][ty + 8 * r]);
}

// ---------- weight repack (O,I,3,3) f32 -> [k][oc][ic] bf16 ----------
__global__ __launch_bounds__(256) void repack3(const float* __restrict__ w,
                                               unsigned short* __restrict__ o) {
    int t = blockIdx.x * 256 + threadIdx.x;          // < 589824
    int ic = t & 255, oc = (t >> 8) & 255, k = t >> 16;
    o[t] = f2bf(w[((size_t)(oc * Cn + ic)) * 9 + k]);
}

// ---------- head weight repack (OC,256) f32 -> [PM][256] bf16 zero-padded ----------
template <int OC, int PM>
__global__ __launch_bounds__(256) void repackHead(const float* __restrict__ w,
                                                  unsigned short* __restrict__ o) {
    int t = blockIdx.x * 256 + threadIdx.x;   // < PM*256
    int ic = t & 255, oc = t >> 8;
    o[t] = (oc < OC) ? f2bf(w[(size_t)oc * Cn + ic]) : (unsigned short)0;
}

// ---------- implicit-GEMM 3x3 conv, NHWC bf16 -> NHWC bf16, bias+ReLU ----------
// grid (B*H=256, 2), block 256 (4 waves, 2 oc x 2 px), tile 128oc x 128px, BK=64
__global__ __launch_bounds__(256, 2) void convGemm(const unsigned short* __restrict__ feat,
                                                   const unsigned short* __restrict__ Wp,
                                                   const float* __restrict__ bias,
                                                   const unsigned short* __restrict__ zb,
                                                   unsigned short* __restrict__ out) {
    __shared__ __align__(16) unsigned short lA[128 * 64];   // weights [oc][ic]
    __shared__ __align__(16) unsigned short lB[128 * 64];   // feat [px][ic]
    const int tid = threadIdx.x;
    const int l = tid & 63, w = tid >> 6;
    const int w_oc = w & 1, w_px = w >> 1;
    const int ry = blockIdx.x;                    // b*H + y
    const int b = ry >> 7, y = ry & 127;
    const int oc0 = blockIdx.y * 128;
    const int lr = l & 15, lg = l >> 4;

    int rI[4], cI[4], dI[4];
#pragma unroll
    for (int i = 0; i < 4; ++i) {
        int ps = (i * 4 + w) * 64 + l;            // physical 16B slot
        rI[i] = ps >> 3;
        cI[i] = ((ps & 7) ^ (rI[i] & 7)) * 8;     // logical chunk -> elem offset
        dI[i] = (i * 4 + w) * 512;                // LDS elem base (wave-uniform)
    }

    f32x4 acc[4][4];
#pragma unroll
    for (int i = 0; i < 4; ++i)
#pragma unroll
        for (int j = 0; j < 4; ++j) acc[i][j] = (f32x4){0.f, 0.f, 0.f, 0.f};

#pragma unroll 1
    for (int k = 0; k < 9; ++k) {
        const int dy = k / 3 - 1, dx = k % 3 - 1;
        const int yy = y + dy;
        const bool vy = (unsigned)yy < (unsigned)Hn;
        const size_t fbase = ((size_t)(b * Hn + yy)) * Wn;
#pragma unroll 1
        for (int cc = 0; cc < 4; ++cc) {
            const int c0 = cc * 64;
            const unsigned short* wk = Wp + (size_t)k * 65536 + (size_t)oc0 * Cn + c0;
#pragma unroll
            for (int i = 0; i < 4; ++i)
                GLOAD16(wk + rI[i] * Cn + cI[i], &lA[dI[i]]);
#pragma unroll
            for (int i = 0; i < 4; ++i) {
                const int pxs = rI[i] + dx;
                const unsigned short* g = (vy && (unsigned)pxs < (unsigned)Wn)
                    ? feat + ((fbase + pxs) * Cn + c0 + cI[i])
                    : zb;
                GLOAD16(g, &lB[dI[i]]);
            }
            __syncthreads();
#pragma unroll
            for (int h = 0; h < 2; ++h) {
                bf16x8 av[4], bv[4];
#pragma unroll
                for (int fm = 0; fm < 4; ++fm) {
                    const int row = w_oc * 64 + fm * 16 + lr;
                    const int ch = h * 4 + lg;
                    av[fm] = *(const bf16x8*)&lA[row * 64 + ((ch ^ (row & 7)) * 8)];
                }
#pragma unroll
                for (int fn = 0; fn < 4; ++fn) {
                    const int row = w_px * 64 + fn * 16 + lr;
                    const int ch = h * 4 + lg;
                    bv[fn] = *(const bf16x8*)&lB[row * 64 + ((ch ^ (row & 7)) * 8)];
                }
#pragma unroll
                for (int fm = 0; fm < 4; ++fm)
#pragma unroll
                    for (int fn = 0; fn < 4; ++fn)
                        acc[fm][fn] = __builtin_amdgcn_mfma_f32_16x16x32_bf16(
                            av[fm], bv[fn], acc[fm][fn], 0, 0, 0);
            }
            __syncthreads();
        }
    }

#pragma unroll
    for (int fm = 0; fm < 4; ++fm) {
        const int ocb = oc0 + w_oc * 64 + fm * 16 + lg * 4;
        const float b0 = bias[ocb], b1 = bias[ocb + 1], b2 = bias[ocb + 2], b3 = bias[ocb + 3];
#pragma unroll
        for (int fn = 0; fn < 4; ++fn) {
            const int px = w_px * 64 + fn * 16 + lr;
            f32x4 v = acc[fm][fn];
            unsigned u0 = (unsigned)f2bf(fmaxf(v[0] + b0, 0.f)) | ((unsigned)f2bf(fmaxf(v[1] + b1, 0.f)) << 16);
            unsigned u1 = (unsigned)f2bf(fmaxf(v[2] + b2, 0.f)) | ((unsigned)f2bf(fmaxf(v[3] + b3, 0.f)) << 16);
            uint2 st; st.x = u0; st.y = u1;
            *(uint2*)&out[((size_t)ry * Wn + px) * Cn + ocb] = st;
        }
    }
}

// ---------- deformable conv as sampled implicit GEMM ----------
// grid (256), block 512 (8 waves, 4 oc x 2 px), tile 256oc x 128px, BK=64, ReLU out
template <bool HASMASK>
__global__ __launch_bounds__(512, 2) void dcnGemm(const unsigned short* __restrict__ feat, // NHWC bf16
                                                  const float* __restrict__ o27,           // NCHW f32
                                                  const unsigned short* __restrict__ Wp,   // [k][oc][ic] bf16
                                                  unsigned short* __restrict__ out) {
    __shared__ __align__(16) unsigned short lA[256 * 64];
    __shared__ __align__(16) unsigned short lB[128 * 64];
    const int tid = threadIdx.x;
    const int l = tid & 63, w = tid >> 6;
    const int w_oc = w & 3, w_px = w >> 2;
    const int ry = blockIdx.x;
    const int b = ry >> 7, y = ry & 127;
    const int lr = l & 15, lg = l >> 4;

    int rI[4], cI[4], dI[4];
#pragma unroll
    for (int i = 0; i < 4; ++i) {
        int ps = (i * 8 + w) * 64 + l;
        rI[i] = ps >> 3;
        cI[i] = ((ps & 7) ^ (rI[i] & 7)) * 8;
        dI[i] = (i * 8 + w) * 512;
    }

    const int sp = tid >> 2;            // sampled pixel 0..127
    const int pc0 = (tid & 3) * 2;      // physical chunk pair

    f32x4 acc[4][4];
#pragma unroll
    for (int i = 0; i < 4; ++i)
#pragma unroll
        for (int j = 0; j < 4; ++j) acc[i][j] = (f32x4){0.f, 0.f, 0.f, 0.f};

    const unsigned short* fb = feat + (size_t)b * HWn * Cn;
    const float* ob = o27 + (size_t)b * 27 * HWn + y * Wn + sp;

#pragma unroll 1
    for (int k = 0; k < 9; ++k) {
        // bilinear params for (sp, k)
        const float offy = ob[(size_t)(2 * k) * HWn];
        const float offx = ob[(size_t)(2 * k + 1) * HWn];
        const float m = HASMASK ? ob[(size_t)(18 + k) * HWn] : 1.f;
        const float py = (float)(y + k / 3 - 1) + offy;
        const float px = (float)(sp + k % 3 - 1) + offx;
        const float y0f = floorf(py), x0f = floorf(px);
        const float wy1 = py - y0f, wx1 = px - x0f;
        const int iy0 = (int)y0f, ix0 = (int)x0f;
        const int iy1 = iy0 + 1, ix1 = ix0 + 1;
        const bool vy0 = (unsigned)iy0 < (unsigned)Hn, vy1 = (unsigned)iy1 < (unsigned)Hn;
        const bool vx0 = (unsigned)ix0 < (unsigned)Wn, vx1 = (unsigned)ix1 < (unsigned)Wn;
        const int yc0 = min(max(iy0, 0), Hn - 1), yc1 = min(max(iy1, 0), Hn - 1);
        const int xc0 = min(max(ix0, 0), Wn - 1), xc1 = min(max(ix1, 0), Wn - 1);
        const float cw0 = (vy0 && vx0) ? (1.f - wy1) * (1.f - wx1) * m : 0.f;
        const float cw1 = (vy0 && vx1) ? (1.f - wy1) * wx1 * m : 0.f;
        const float cw2 = (vy1 && vx0) ? wy1 * (1.f - wx1) * m : 0.f;
        const float cw3 = (vy1 && vx1) ? wy1 * wx1 * m : 0.f;
        const int ci0 = (yc0 * Wn + xc0) * Cn;
        const int ci1 = (yc0 * Wn + xc1) * Cn;
        const int ci2 = (yc1 * Wn + xc0) * Cn;
        const int ci3 = (yc1 * Wn + xc1) * Cn;

#pragma unroll 1
        for (int cc = 0; cc < 4; ++cc) {
            const int c0 = cc * 64;
            const unsigned short* wk = Wp + (size_t)k * 65536 + c0;
#pragma unroll
            for (int i = 0; i < 4; ++i)
                GLOAD16(wk + rI[i] * Cn + cI[i], &lA[dI[i]]);
            // sampled feat tile: 2 slots per thread, reg-staged ds_write
#pragma unroll
            for (int s = 0; s < 2; ++s) {
                const int pcS = pc0 + s;
                const int cb = c0 + ((pcS ^ (sp & 7)) * 8);
                int4 q0 = *(const int4*)(fb + ci0 + cb);
                int4 q1 = *(const int4*)(fb + ci1 + cb);
                int4 q2 = *(const int4*)(fb + ci2 + cb);
                int4 q3 = *(const int4*)(fb + ci3 + cb);
                float f0[8], f1[8], f2[8], f3[8];
                unp8(q0, f0); unp8(q1, f1); unp8(q2, f2); unp8(q3, f3);
                unsigned u[4];
#pragma unroll
                for (int jj = 0; jj < 4; ++jj) {
                    float e0 = cw0 * f0[2 * jj] + cw1 * f1[2 * jj] + cw2 * f2[2 * jj] + cw3 * f3[2 * jj];
                    float e1 = cw0 * f0[2 * jj + 1] + cw1 * f1[2 * jj + 1] + cw2 * f2[2 * jj + 1] + cw3 * f3[2 * jj + 1];
                    u[jj] = (unsigned)f2bf(e0) | ((unsigned)f2bf(e1) << 16);
                }
                int4 pk; pk.x = u[0]; pk.y = u[1]; pk.z = u[2]; pk.w = u[3];
                *(int4*)&lB[sp * 64 + pcS * 8] = pk;
            }
            __syncthreads();
#pragma unroll
            for (int h = 0; h < 2; ++h) {
                bf16x8 av[4], bv[4];
#pragma unroll
                for (int fm = 0; fm < 4; ++fm) {
                    const int row = w_oc * 64 + fm * 16 + lr;
                    const int ch = h * 4 + lg;
                    av[fm] = *(const bf16x8*)&lA[row * 64 + ((ch ^ (row & 7)) * 8)];
                }
#pragma unroll
                for (int fn = 0; fn < 4; ++fn) {
                    const int row = w_px * 64 + fn * 16 + lr;
                    const int ch = h * 4 + lg;
                    bv[fn] = *(const bf16x8*)&lB[row * 64 + ((ch ^ (row & 7)) * 8)];
                }
#pragma unroll
                for (int fm = 0; fm < 4; ++fm)
#pragma unroll
                    for (int fn = 0; fn < 4; ++fn)
                        acc[fm][fn] = __builtin_amdgcn_mfma_f32_16x16x32_bf16(
                            av[fm], bv[fn], acc[fm][fn], 0, 0, 0);
            }
            __syncthreads();
        }
    }

#pragma unroll
    for (int fm = 0; fm < 4; ++fm) {
        const int ocb = w_oc * 64 + fm * 16 + lg * 4;
#pragma unroll
        for (int fn = 0; fn < 4; ++fn) {
            const int px = w_px * 64 + fn * 16 + lr;
            f32x4 v = acc[fm][fn];
            unsigned u0 = (unsigned)f2bf(fmaxf(v[0], 0.f)) | ((unsigned)f2bf(fmaxf(v[1], 0.f)) << 16);
            unsigned u1 = (unsigned)f2bf(fmaxf(v[2], 0.f)) | ((unsigned)f2bf(fmaxf(v[3], 0.f)) << 16);
            uint2 st; st.x = u0; st.y = u1;
            *(uint2*)&out[((size_t)ry * Wn + px) * Cn + ocb] = st;
        }
    }
}

// ---------- MFMA 1x1 head: NHWC bf16 in, NCHW f32 out (+bias, +optional add) ----------
// grid (B*H=256), block 256 (4 waves over px), tile PMoc x 128px, BK=64
template <int OC, int PM, bool ADD>
__global__ __launch_bounds__(256, 2) void headGemm(const unsigned short* __restrict__ feat,
                                                   const unsigned short* __restrict__ Wp,   // [PM][256] bf16
                                                   const float* __restrict__ bias,
                                                   float* __restrict__ out,
                                                   const float* __restrict__ add,
                                                   int addC) {
    constexpr int MF = PM / 16;          // m-fragments
    constexpr int NA = PM * 8 / 256;     // A staging iterations
    __shared__ __align__(16) unsigned short lA[PM * 64];
    __shared__ __align__(16) unsigned short lB[128 * 64];
    const int tid = threadIdx.x;
    const int l = tid & 63, w = tid >> 6;   // w = w_px (0..3)
    const int ry = blockIdx.x;
    const int b = ry >> 7, y = ry & 127;
    const int lr = l & 15, lg = l >> 4;

    int rIA[NA], cIA[NA], dIA[NA];
#pragma unroll
    for (int i = 0; i < NA; ++i) {
        int ps = (i * 4 + w) * 64 + l;
        rIA[i] = ps >> 3;
        cIA[i] = ((ps & 7) ^ (rIA[i] & 7)) * 8;
        dIA[i] = (i * 4 + w) * 512;
    }
    int rIB[4], cIB[4], dIB[4];
#pragma unroll
    for (int i = 0; i < 4; ++i) {
        int ps = (i * 4 + w) * 64 + l;
        rIB[i] = ps >> 3;
        cIB[i] = ((ps & 7) ^ (rIB[i] & 7)) * 8;
        dIB[i] = (i * 4 + w) * 512;
    }

    f32x4 acc[MF][2];
#pragma unroll
    for (int i = 0; i < MF; ++i)
#pragma unroll
        for (int j = 0; j < 2; ++j) acc[i][j] = (f32x4){0.f, 0.f, 0.f, 0.f};

    const unsigned short* frow = feat + ((size_t)ry * Wn) * Cn;

#pragma unroll 1
    for (int cc = 0; cc < 4; ++cc) {
        const int c0 = cc * 64;
#pragma unroll
        for (int i = 0; i < NA; ++i)
            GLOAD16(Wp + (size_t)rIA[i] * Cn + c0 + cIA[i], &lA[dIA[i]]);
#pragma unroll
        for (int i = 0; i < 4; ++i)
            GLOAD16(frow + (size_t)rIB[i] * Cn + c0 + cIB[i], &lB[dIB[i]]);
        __syncthreads();
#pragma unroll
        for (int h = 0; h < 2; ++h) {
            const int ch = h * 4 + lg;
            bf16x8 av[MF], bv[2];
#pragma unroll
            for (int fm = 0; fm < MF; ++fm) {
                const int row = fm * 16 + lr;
                av[fm] = *(const bf16x8*)&lA[row * 64 + ((ch ^ (row & 7)) * 8)];
            }
#pragma unroll
            for (int fn = 0; fn < 2; ++fn) {
                const int row = w * 32 + fn * 16 + lr;
                bv[fn] = *(const bf16x8*)&lB[row * 64 + ((ch ^ (row & 7)) * 8)];
            }
#pragma unroll
            for (int fm = 0; fm < MF; ++fm)
#pragma unroll
                for (int fn = 0; fn < 2; ++fn)
                    acc[fm][fn] = __builtin_amdgcn_mfma_f32_16x16x32_bf16(
                        av[fm], bv[fn], acc[fm][fn], 0, 0, 0);
        }
        __syncthreads();
    }

#pragma unroll
    for (int fm = 0; fm < MF; ++fm) {
        const int ocb = fm * 16 + lg * 4;
        if (ocb >= OC) break;
#pragma unroll
        for (int j = 0; j < 4; ++j) {
            const int oc = ocb + j;
            if (oc >= OC) break;
            const float bs = bias[oc];
#pragma unroll
            for (int fn = 0; fn < 2; ++fn) {
                const int px = w * 32 + fn * 16 + lr;
                float r = acc[fm][fn][j] + bs;
                const size_t oidx = ((size_t)(b * OC + oc)) * HWn + y * Wn + px;
                if (ADD) r += add[((size_t)(b * addC + oc)) * HWn + y * Wn + px];
                out[oidx] = r;
            }
        }
    }
}

// ---------- postproc ----------
__global__ __launch_bounds__(256) void postK(const float* __restrict__ r18,
                                             float* __restrict__ wh,
                                             float* __restrict__ reg) {
    const int hw = (blockIdx.x & 63) * 256 + threadIdx.x;
    const int b = blockIdx.x >> 6;
    const float* p = r18 + (size_t)(b * 18) * HWn + hw;
    float v[18];
#pragma unroll
    for (int c = 0; c < 18; ++c) v[c] = p[(size_t)c * HWn];
    float s0 = 0.f, s1 = 0.f;
#pragma unroll
    for (int q = 0; q < 9; ++q) { s0 += v[2 * q]; s1 += v[2 * q + 1]; }
    float m0 = s0 * (1.f / 9.f), m1 = s1 * (1.f / 9.f);
    float w0 = 0.f, w1 = 0.f;
#pragma unroll
    for (int q = 0; q < 9; ++q) {
        w0 = fmaxf(w0, fabsf(v[2 * q] + m0));
        w1 = fmaxf(w1, fabsf(v[2 * q + 1] + m1));
    }
    wh[(size_t)(b * 2 + 0) * HWn + hw] = w0;
    wh[(size_t)(b * 2 + 1) * HWn + hw] = w1;
    reg[(size_t)(b * 2 + 0) * HWn + hw] = m0;
    reg[(size_t)(b * 2 + 1) * HWn + hw] = m1;
}

// ---------- host ----------
extern "C" void kernel_launch(void* const* d_in, const int* in_sizes, int n_in,
                              void* d_out, int out_size, void* d_ws, size_t ws_size,
                              hipStream_t stream) {
    const float* x           = (const float*)d_in[0];
    const float* cls_w0      = (const float*)d_in[1];
    const float* cls_b0      = (const float*)d_in[2];
    const float* reg_w0      = (const float*)d_in[3];
    const float* reg_b0      = (const float*)d_in[4];
    const float* cls_w1      = (const float*)d_in[5];
    const float* cls_b1      = (const float*)d_in[6];
    const float* reg_w1      = (const float*)d_in[7];
    const float* reg_b1      = (const float*)d_in[8];
    const float* cls_w2      = (const float*)d_in[9];
    const float* cls_b2      = (const float*)d_in[10];
    const float* reg_w2      = (const float*)d_in[11];
    const float* reg_b2      = (const float*)d_in[12];
    const float* init_conv_w = (const float*)d_in[13];
    const float* init_conv_b = (const float*)d_in[14];
    const float* init_out_w  = (const float*)d_in[15];
    const float* init_out_b  = (const float*)d_in[16];
    const float* dcn_cls_w   = (const float*)d_in[17];
    const float* cls_out_w   = (const float*)d_in[18];
    const float* cls_out_b   = (const float*)d_in[19];
    const float* dcn_ref_w   = (const float*)d_in[20];
    const float* ref_out_w   = (const float*)d_in[21];
    const float* ref_out_b   = (const float*)d_in[22];

    float* out = (float*)d_out;

    char* ws = (char*)d_ws;
    const size_t IMG = (size_t)Bn * HWn * Cn * sizeof(unsigned short);  // 16 MiB
    unsigned short* Xb  = (unsigned short*)ws; ws += IMG;
    unsigned short* T1  = (unsigned short*)ws; ws += IMG;
    unsigned short* T2  = (unsigned short*)ws; ws += IMG;
    unsigned short* CLS = (unsigned short*)ws; ws += IMG;
    unsigned short* PTS = (unsigned short*)ws; ws += IMG;
    float* O27 = (float*)ws; ws += (size_t)Bn * 27 * HWn * sizeof(float);
    float* R18 = (float*)ws; ws += (size_t)Bn * 18 * HWn * sizeof(float);
    const size_t WSZ = (size_t)9 * Cn * Cn;   // 589824 elems per weight
    unsigned short* Wpk = (unsigned short*)ws; ws += 9 * WSZ * sizeof(unsigned short);
    unsigned short* Wh27 = (unsigned short*)ws; ws += 32 * Cn * sizeof(unsigned short);
    unsigned short* Wh80 = (unsigned short*)ws; ws += 96 * Cn * sizeof(unsigned short);
    unsigned short* Wh18 = (unsigned short*)ws; ws += 32 * Cn * sizeof(unsigned short);
    unsigned short* ZB = (unsigned short*)ws;  ws += 512;

    unsigned short* W_cls0 = Wpk + 0 * WSZ;
    unsigned short* W_cls1 = Wpk + 1 * WSZ;
    unsigned short* W_cls2 = Wpk + 2 * WSZ;
    unsigned short* W_reg0 = Wpk + 3 * WSZ;
    unsigned short* W_reg1 = Wpk + 4 * WSZ;
    unsigned short* W_reg2 = Wpk + 5 * WSZ;
    unsigned short* W_init = Wpk + 6 * WSZ;
    unsigned short* W_dcls = Wpk + 7 * WSZ;
    unsigned short* W_dref = Wpk + 8 * WSZ;

    const dim3 blk(256);
    const dim3 cgrd(256, 2);
    const dim3 xgrd(512, 8, Bn);

    zeroK<<<1, 128, 0, stream>>>(ZB);
    repack3<<<2304, blk, 0, stream>>>(cls_w0, W_cls0);
    repack3<<<2304, blk, 0, stream>>>(cls_w1, W_cls1);
    repack3<<<2304, blk, 0, stream>>>(cls_w2, W_cls2);
    repack3<<<2304, blk, 0, stream>>>(reg_w0, W_reg0);
    repack3<<<2304, blk, 0, stream>>>(reg_w1, W_reg1);
    repack3<<<2304, blk, 0, stream>>>(reg_w2, W_reg2);
    repack3<<<2304, blk, 0, stream>>>(init_conv_w, W_init);
    repack3<<<2304, blk, 0, stream>>>(dcn_cls_w, W_dcls);
    repack3<<<2304, blk, 0, stream>>>(dcn_ref_w, W_dref);
    repackHead<27, 32><<<32, blk, 0, stream>>>(init_out_w, Wh27);
    repackHead<80, 96><<<96, blk, 0, stream>>>(cls_out_w, Wh80);
    repackHead<18, 32><<<32, blk, 0, stream>>>(ref_out_w, Wh18);
    xinK<<<xgrd, blk, 0, stream>>>(x, Xb);

    // cls tower
    convGemm<<<cgrd, blk, 0, stream>>>(Xb, W_cls0, cls_b0, ZB, T1);
    convGemm<<<cgrd, blk, 0, stream>>>(T1, W_cls1, cls_b1, ZB, T2);
    convGemm<<<cgrd, blk, 0, stream>>>(T2, W_cls2, cls_b2, ZB, CLS);
    // reg tower
    convGemm<<<cgrd, blk, 0, stream>>>(Xb, W_reg0, reg_b0, ZB, T1);
    convGemm<<<cgrd, blk, 0, stream>>>(T1, W_reg1, reg_b1, ZB, T2);
    convGemm<<<cgrd, blk, 0, stream>>>(T2, W_reg2, reg_b2, ZB, PTS);
    // init head
    convGemm<<<cgrd, blk, 0, stream>>>(PTS, W_init, init_conv_b, ZB, T1);
    headGemm<27, 32, false><<<256, blk, 0, stream>>>(T1, Wh27, init_out_b, O27, nullptr, 0);
    // cls branch
    dcnGemm<true><<<256, dim3(512), 0, stream>>>(CLS, O27, W_dcls, T2);
    headGemm<80, 96, false><<<256, blk, 0, stream>>>(T2, Wh80, cls_out_b, out, nullptr, 0);
    // refine branch
    dcnGemm<false><<<256, dim3(512), 0, stream>>>(PTS, O27, W_dref, T1);
    headGemm<18, 32, true><<<256, blk, 0, stream>>>(T1, Wh18, ref_out_b, R18, O27, 27);

    postK<<<128, blk, 0, stream>>>(R18,
                                   out + (size_t)Bn * NCn * HWn,
                                   out + (size_t)Bn * NCn * HWn + (size_t)Bn * 2 * HWn);
}

// Round 4
// 611.427 us; speedup vs baseline: 17.4124x; 1.0763x over previous
//
#include <hip/hip_runtime.h>

#define Bn 2
#define Cn 256
#define Hn 128
#define Wn 128
#define HWn 16384
#define NCn 80

typedef __attribute__((ext_vector_type(4))) float f32x4;
typedef __attribute__((ext_vector_type(8))) short bf16x8;

__device__ __forceinline__ float b2f(unsigned short h) {
    union { unsigned u; float f; } x; x.u = ((unsigned)h) << 16; return x.f;
}
__device__ __forceinline__ float blo(unsigned u) {
    union { unsigned u; float f; } x; x.u = u << 16; return x.f;
}
__device__ __forceinline__ float bhi(unsigned u) {
    union { unsigned u; float f; } x; x.u = u & 0xffff0000u; return x.f;
}
__device__ __forceinline__ unsigned short f2bf(float f) {
    union { float f; unsigned u; } x; x.f = f;
    unsigned u = x.u + 0x7fffu + ((x.u >> 16) & 1u);   // RNE
    return (unsigned short)(u >> 16);
}

// async global->LDS, 16B per lane, wave-uniform LDS base + lane*16
#define GLOAD16(gp, lp) __builtin_amdgcn_global_load_lds( \
    (__attribute__((address_space(1))) unsigned int*)(gp), \
    (__attribute__((address_space(3))) unsigned int*)(lp), 16, 0, 0)

// ---------- zero scratch ----------
__global__ void zeroK(unsigned short* z) { z[threadIdx.x] = 0; }

// ---------- x (NCHW f32) -> NHWC bf16 ----------
__global__ __launch_bounds__(256) void xinK(const float* __restrict__ x,
                                            unsigned short* __restrict__ o) {
    __shared__ float tb[32][33];
    const int b = blockIdx.z;
    const int hw0 = blockIdx.x * 32, c0 = blockIdx.y * 32;
    const int tx = threadIdx.x & 31, ty = threadIdx.x >> 5;
    const float* ip = x + ((size_t)(b * Cn + c0)) * HWn + hw0;
#pragma unroll
    for (int r = 0; r < 4; ++r) tb[ty + 8 * r][tx] = ip[(size_t)(ty + 8 * r) * HWn + tx];
    __syncthreads();
    unsigned short* op = o + ((size_t)(b * HWn + hw0)) * Cn + c0;
#pragma unroll
    for (int r = 0; r < 4; ++r) op[(size_t)(ty + 8 * r) * Cn + tx] = f2bf(tb[tx][ty + 8 * r]);
}

// ---------- fused weight repack: 9x (O,I,3,3) f32 -> [w][k][oc][ic] bf16 ----------
struct WPtrs { const float* p[9]; };
__global__ __launch_bounds__(256) void repackAll(WPtrs wsrc, unsigned short* __restrict__ dst) {
    const int widx = blockIdx.y;
    const int t = blockIdx.x * 256 + threadIdx.x;     // < 589824
    const int ic = t & 255, oc = (t >> 8) & 255, k = t >> 16;
    dst[(size_t)widx * 589824 + t] = f2bf(wsrc.p[widx][((size_t)(oc * Cn + ic)) * 9 + k]);
}

// ---------- fused head repack: rows [0,32)=w27, [32,128)=w80, [128,160)=w18 ----------
struct HPtrs { const float* w[3]; };
__global__ __launch_bounds__(256) void repackHeads(HPtrs hs, unsigned short* __restrict__ dst) {
    const int t = blockIdx.x * 256 + threadIdx.x;     // < 160*256
    const int ic = t & 255, row = t >> 8;
    int which, oc, OC;
    if (row < 32)       { which = 0; oc = row;       OC = 27; }
    else if (row < 128) { which = 1; oc = row - 32;  OC = 80; }
    else                { which = 2; oc = row - 128; OC = 18; }
    dst[t] = (oc < OC) ? f2bf(hs.w[which][(size_t)oc * Cn + ic]) : (unsigned short)0;
}

// ---------- implicit-GEMM 3x3 conv, NHWC bf16 -> NHWC bf16, bias+ReLU ----------
// grid (256, 2), block 256 (4 waves, 2 oc x 2 px), tile 128oc x 128px, BK=64
// 2-phase double-buffered pipeline, one barrier per phase, XCD-swizzled rows.
__global__ __launch_bounds__(256, 2) void convGemm(const unsigned short* __restrict__ feat,
                                                   const unsigned short* __restrict__ Wp,
                                                   const float* __restrict__ bias,
                                                   const unsigned short* __restrict__ zb,
                                                   unsigned short* __restrict__ out) {
    __shared__ __align__(16) unsigned short lA[2][8192];   // weights [oc][ic]
    __shared__ __align__(16) unsigned short lB[2][8192];   // feat [px][ic]
    const int tid = threadIdx.x;
    const int l = tid & 63, w = tid >> 6;
    const int w_oc = w & 1, w_px = w >> 1;
    const int ry = (blockIdx.x & 7) * 32 + (blockIdx.x >> 3);   // XCD-chunked rows
    const int b = ry >> 7, y = ry & 127;
    const int oc0 = blockIdx.y * 128;
    const int lr = l & 15, lg = l >> 4;

    int rI[4], cI[4], dI[4];
#pragma unroll
    for (int i = 0; i < 4; ++i) {
        int ps = (i * 4 + w) * 64 + l;            // physical 16B slot
        rI[i] = ps >> 3;
        cI[i] = ((ps & 7) ^ (rI[i] & 7)) * 8;     // pre-swizzled source chunk
        dI[i] = (i * 4 + w) * 512;                // wave-uniform LDS elem base
    }

    f32x4 acc[4][4];
#pragma unroll
    for (int i = 0; i < 4; ++i)
#pragma unroll
        for (int j = 0; j < 4; ++j) acc[i][j] = (f32x4){0.f, 0.f, 0.f, 0.f};

    auto stage = [&](int p, int bufIdx) {
        const int k = p >> 2, c0 = (p & 3) * 64;
        const int dy = k / 3 - 1, dx = k % 3 - 1;
        const int yy = y + dy;
        const bool vy = (unsigned)yy < (unsigned)Hn;
        const size_t fbase = ((size_t)(b * Hn + yy)) * Wn;
        const unsigned short* wk = Wp + (size_t)k * 65536 + (size_t)oc0 * Cn + c0;
        unsigned short* la = lA[bufIdx];
        unsigned short* lb = lB[bufIdx];
#pragma unroll
        for (int i = 0; i < 4; ++i)
            GLOAD16(wk + rI[i] * Cn + cI[i], la + dI[i]);
#pragma unroll
        for (int i = 0; i < 4; ++i) {
            const int pxs = rI[i] + dx;
            const unsigned short* g = (vy && (unsigned)pxs < (unsigned)Wn)
                ? feat + ((fbase + pxs) * Cn + c0 + cI[i])
                : zb;
            GLOAD16(g, lb + dI[i]);
        }
    };

    stage(0, 0);
    __syncthreads();          // drains vmcnt -> buf0 ready

#pragma unroll 1
    for (int p = 0; p < 36; ++p) {
        const int cur = p & 1;
        if (p < 35) stage(p + 1, cur ^ 1);      // async, overlaps MFMA below
        const unsigned short* la = lA[cur];
        const unsigned short* lb = lB[cur];
#pragma unroll
        for (int h = 0; h < 2; ++h) {
            const int ch = h * 4 + lg;
            bf16x8 av[4], bv[4];
#pragma unroll
            for (int fm = 0; fm < 4; ++fm) {
                const int row = w_oc * 64 + fm * 16 + lr;
                av[fm] = *(const bf16x8*)&la[row * 64 + ((ch ^ (row & 7)) * 8)];
            }
#pragma unroll
            for (int fn = 0; fn < 4; ++fn) {
                const int row = w_px * 64 + fn * 16 + lr;
                bv[fn] = *(const bf16x8*)&lb[row * 64 + ((ch ^ (row & 7)) * 8)];
            }
#pragma unroll
            for (int fm = 0; fm < 4; ++fm)
#pragma unroll
                for (int fn = 0; fn < 4; ++fn)
                    acc[fm][fn] = __builtin_amdgcn_mfma_f32_16x16x32_bf16(
                        av[fm], bv[fn], acc[fm][fn], 0, 0, 0);
        }
        __syncthreads();      // vmcnt(0)+barrier: staged buf ready for next iter
    }

#pragma unroll
    for (int fm = 0; fm < 4; ++fm) {
        const int ocb = oc0 + w_oc * 64 + fm * 16 + lg * 4;
        const float b0 = bias[ocb], b1 = bias[ocb + 1], b2 = bias[ocb + 2], b3 = bias[ocb + 3];
#pragma unroll
        for (int fn = 0; fn < 4; ++fn) {
            const int px = w_px * 64 + fn * 16 + lr;
            f32x4 v = acc[fm][fn];
            unsigned u0 = (unsigned)f2bf(fmaxf(v[0] + b0, 0.f)) | ((unsigned)f2bf(fmaxf(v[1] + b1, 0.f)) << 16);
            unsigned u1 = (unsigned)f2bf(fmaxf(v[2] + b2, 0.f)) | ((unsigned)f2bf(fmaxf(v[3] + b3, 0.f)) << 16);
            uint2 st; st.x = u0; st.y = u1;
            *(uint2*)&out[((size_t)ry * Wn + px) * Cn + ocb] = st;
        }
    }
}

// ---------- deformable conv as sampled implicit GEMM ----------
// grid (512), block 512 (8 waves, 4 oc x 2 px), tile 256oc x 64px, BK=64, ReLU out
// 2-phase double buffer; swizzled ds_write (conflict-free); XCD-chunked.
template <bool HASMASK>
__global__ __launch_bounds__(512, 4) void dcnGemm(const unsigned short* __restrict__ feat, // NHWC bf16
                                                  const float* __restrict__ o27,           // NCHW f32
                                                  const unsigned short* __restrict__ Wp,   // [k][oc][ic] bf16
                                                  unsigned short* __restrict__ out) {
    __shared__ __align__(16) unsigned short lA[2][16384];   // 256oc x 64ch
    __shared__ __align__(16) unsigned short lB[2][4096];    // 64px x 64ch
    const int tid = threadIdx.x;
    const int l = tid & 63, w = tid >> 6;
    const int w_oc = w & 3, w_px = w >> 2;
    const int g = (blockIdx.x & 7) * 64 + (blockIdx.x >> 3);  // XCD-chunked
    const int ry = g >> 1, st = g & 1;
    const int b = ry >> 7, y = ry & 127;
    const int x0 = st * 64;
    const int lr = l & 15, lg = l >> 4;

    int rIA[4], cIA[4], dIA[4];
#pragma unroll
    for (int i = 0; i < 4; ++i) {
        int ps = (i * 8 + w) * 64 + l;            // 2048 slots (256 rows x 8)
        rIA[i] = ps >> 3;
        cIA[i] = ((ps & 7) ^ (rIA[i] & 7)) * 8;
        dIA[i] = (i * 8 + w) * 512;
    }

    const int sp = tid >> 3;          // sampled px 0..63
    const int pc = tid & 7;           // chunk 0..7
    const int xg = x0 + sp;

    const float* ob = o27 + (size_t)b * 27 * HWn + y * Wn + xg;
    const unsigned short* fb = feat + (size_t)b * HWn * Cn;

    f32x4 acc[4][2];
#pragma unroll
    for (int i = 0; i < 4; ++i)
#pragma unroll
        for (int j = 0; j < 2; ++j) acc[i][j] = (f32x4){0.f, 0.f, 0.f, 0.f};

    int ci0, ci1, ci2, ci3;
    float cw0, cw1, cw2, cw3;

    auto sampParams = [&](int k) {
        const float offy = ob[(size_t)(2 * k) * HWn];
        const float offx = ob[(size_t)(2 * k + 1) * HWn];
        const float m = HASMASK ? ob[(size_t)(18 + k) * HWn] : 1.f;
        const float py = (float)(y + k / 3 - 1) + offy;
        const float px = (float)(xg + k % 3 - 1) + offx;
        const float y0f = floorf(py), x0f = floorf(px);
        const float wy1 = py - y0f, wx1 = px - x0f;
        const int iy0 = (int)y0f, ix0 = (int)x0f;
        const int iy1 = iy0 + 1, ix1 = ix0 + 1;
        const bool vy0 = (unsigned)iy0 < (unsigned)Hn, vy1 = (unsigned)iy1 < (unsigned)Hn;
        const bool vx0 = (unsigned)ix0 < (unsigned)Wn, vx1 = (unsigned)ix1 < (unsigned)Wn;
        const int yc0 = min(max(iy0, 0), Hn - 1), yc1 = min(max(iy1, 0), Hn - 1);
        const int xc0 = min(max(ix0, 0), Wn - 1), xc1 = min(max(ix1, 0), Wn - 1);
        cw0 = (vy0 && vx0) ? (1.f - wy1) * (1.f - wx1) * m : 0.f;
        cw1 = (vy0 && vx1) ? (1.f - wy1) * wx1 * m : 0.f;
        cw2 = (vy1 && vx0) ? wy1 * (1.f - wx1) * m : 0.f;
        cw3 = (vy1 && vx1) ? wy1 * wx1 * m : 0.f;
        ci0 = (yc0 * Wn + xc0) * Cn;
        ci1 = (yc0 * Wn + xc1) * Cn;
        ci2 = (yc1 * Wn + xc0) * Cn;
        ci3 = (yc1 * Wn + xc1) * Cn;
    };

    auto stage = [&](int p, int bufIdx) {
        const int k = p >> 2, c0 = (p & 3) * 64;
        const unsigned short* wk = Wp + (size_t)k * 65536 + c0;
        unsigned short* la = lA[bufIdx];
#pragma unroll
        for (int i = 0; i < 4; ++i)
            GLOAD16(wk + rIA[i] * Cn + cIA[i], la + dIA[i]);
        if ((p & 3) == 0) sampParams(k);
        const int cb = c0 + pc * 8;               // linear global chunk (coalesced pairs)
        int4 q0 = *(const int4*)(fb + ci0 + cb);
        int4 q1 = *(const int4*)(fb + ci1 + cb);
        int4 q2 = *(const int4*)(fb + ci2 + cb);
        int4 q3 = *(const int4*)(fb + ci3 + cb);
        unsigned u[4];
#pragma unroll
        for (int jj = 0; jj < 4; ++jj) {
            const unsigned a0 = ((const unsigned*)&q0)[jj];
            const unsigned a1 = ((const unsigned*)&q1)[jj];
            const unsigned a2 = ((const unsigned*)&q2)[jj];
            const unsigned a3 = ((const unsigned*)&q3)[jj];
            float e0 = cw0 * blo(a0) + cw1 * blo(a1) + cw2 * blo(a2) + cw3 * blo(a3);
            float e1 = cw0 * bhi(a0) + cw1 * bhi(a1) + cw2 * bhi(a2) + cw3 * bhi(a3);
            u[jj] = (unsigned)f2bf(e0) | ((unsigned)f2bf(e1) << 16);
        }
        int4 pk; pk.x = u[0]; pk.y = u[1]; pk.z = u[2]; pk.w = u[3];
        // swizzled WRITE slot (pc ^ sp) -> read formula (ch ^ row) matches
        *(int4*)&lB[bufIdx][sp * 64 + ((pc ^ (sp & 7)) * 8)] = pk;
    };

    stage(0, 0);
    __syncthreads();

#pragma unroll 1
    for (int p = 0; p < 36; ++p) {
        const int cur = p & 1;
        if (p < 35) stage(p + 1, cur ^ 1);
        const unsigned short* la = lA[cur];
        const unsigned short* lb = lB[cur];
#pragma unroll
        for (int h = 0; h < 2; ++h) {
            const int ch = h * 4 + lg;
            bf16x8 av[4], bv[2];
#pragma unroll
            for (int fm = 0; fm < 4; ++fm) {
                const int row = w_oc * 64 + fm * 16 + lr;
                av[fm] = *(const bf16x8*)&la[row * 64 + ((ch ^ (row & 7)) * 8)];
            }
#pragma unroll
            for (int fn = 0; fn < 2; ++fn) {
                const int row = w_px * 32 + fn * 16 + lr;
                bv[fn] = *(const bf16x8*)&lb[row * 64 + ((ch ^ (row & 7)) * 8)];
            }
#pragma unroll
            for (int fm = 0; fm < 4; ++fm)
#pragma unroll
                for (int fn = 0; fn < 2; ++fn)
                    acc[fm][fn] = __builtin_amdgcn_mfma_f32_16x16x32_bf16(
                        av[fm], bv[fn], acc[fm][fn], 0, 0, 0);
        }
        __syncthreads();
    }

#pragma unroll
    for (int fm = 0; fm < 4; ++fm) {
        const int ocb = w_oc * 64 + fm * 16 + lg * 4;
#pragma unroll
        for (int fn = 0; fn < 2; ++fn) {
            const int px = x0 + w_px * 32 + fn * 16 + lr;
            f32x4 v = acc[fm][fn];
            unsigned u0 = (unsigned)f2bf(fmaxf(v[0], 0.f)) | ((unsigned)f2bf(fmaxf(v[1], 0.f)) << 16);
            unsigned u1 = (unsigned)f2bf(fmaxf(v[2], 0.f)) | ((unsigned)f2bf(fmaxf(v[3], 0.f)) << 16);
            uint2 stv; stv.x = u0; stv.y = u1;
            *(uint2*)&out[((size_t)ry * Wn + px) * Cn + ocb] = stv;
        }
    }
}

// ---------- MFMA 1x1 head: NHWC bf16 in, NCHW f32 out (+bias, +optional add) ----------
// grid (256), block 256 (4 waves over px), tile PMoc x 128px, BK=64
template <int OC, int PM, bool ADD>
__global__ __launch_bounds__(256, 2) void headGemm(const unsigned short* __restrict__ feat,
                                                   const unsigned short* __restrict__ Wp,   // [PM][256] bf16
                                                   const float* __restrict__ bias,
                                                   float* __restrict__ out,
                                                   const float* __restrict__ add,
                                                   int addC) {
    constexpr int MF = PM / 16;
    constexpr int NA = PM * 8 / 256;
    __shared__ __align__(16) unsigned short lA[PM * 64];
    __shared__ __align__(16) unsigned short lB[128 * 64];
    const int tid = threadIdx.x;
    const int l = tid & 63, w = tid >> 6;
    const int ry = (blockIdx.x & 7) * 32 + (blockIdx.x >> 3);
    const int b = ry >> 7, y = ry & 127;
    const int lr = l & 15, lg = l >> 4;

    int rIA[NA], cIA[NA], dIA[NA];
#pragma unroll
    for (int i = 0; i < NA; ++i) {
        int ps = (i * 4 + w) * 64 + l;
        rIA[i] = ps >> 3;
        cIA[i] = ((ps & 7) ^ (rIA[i] & 7)) * 8;
        dIA[i] = (i * 4 + w) * 512;
    }
    int rIB[4], cIB[4], dIB[4];
#pragma unroll
    for (int i = 0; i < 4; ++i) {
        int ps = (i * 4 + w) * 64 + l;
        rIB[i] = ps >> 3;
        cIB[i] = ((ps & 7) ^ (rIB[i] & 7)) * 8;
        dIB[i] = (i * 4 + w) * 512;
    }

    f32x4 acc[MF][2];
#pragma unroll
    for (int i = 0; i < MF; ++i)
#pragma unroll
        for (int j = 0; j < 2; ++j) acc[i][j] = (f32x4){0.f, 0.f, 0.f, 0.f};

    const unsigned short* frow = feat + ((size_t)ry * Wn) * Cn;

#pragma unroll 1
    for (int cc = 0; cc < 4; ++cc) {
        const int c0 = cc * 64;
#pragma unroll
        for (int i = 0; i < NA; ++i)
            GLOAD16(Wp + (size_t)rIA[i] * Cn + c0 + cIA[i], &lA[dIA[i]]);
#pragma unroll
        for (int i = 0; i < 4; ++i)
            GLOAD16(frow + (size_t)rIB[i] * Cn + c0 + cIB[i], &lB[dIB[i]]);
        __syncthreads();
#pragma unroll
        for (int h = 0; h < 2; ++h) {
            const int ch = h * 4 + lg;
            bf16x8 av[MF], bv[2];
#pragma unroll
            for (int fm = 0; fm < MF; ++fm) {
                const int row = fm * 16 + lr;
                av[fm] = *(const bf16x8*)&lA[row * 64 + ((ch ^ (row & 7)) * 8)];
            }
#pragma unroll
            for (int fn = 0; fn < 2; ++fn) {
                const int row = w * 32 + fn * 16 + lr;
                bv[fn] = *(const bf16x8*)&lB[row * 64 + ((ch ^ (row & 7)) * 8)];
            }
#pragma unroll
            for (int fm = 0; fm < MF; ++fm)
#pragma unroll
                for (int fn = 0; fn < 2; ++fn)
                    acc[fm][fn] = __builtin_amdgcn_mfma_f32_16x16x32_bf16(
                        av[fm], bv[fn], acc[fm][fn], 0, 0, 0);
        }
        __syncthreads();
    }

#pragma unroll
    for (int fm = 0; fm < MF; ++fm) {
        const int ocb = fm * 16 + lg * 4;
        if (ocb >= OC) break;
#pragma unroll
        for (int j = 0; j < 4; ++j) {
            const int oc = ocb + j;
            if (oc >= OC) break;
            const float bs = bias[oc];
#pragma unroll
            for (int fn = 0; fn < 2; ++fn) {
                const int px = w * 32 + fn * 16 + lr;
                float r = acc[fm][fn][j] + bs;
                const size_t oidx = ((size_t)(b * OC + oc)) * HWn + y * Wn + px;
                if (ADD) r += add[((size_t)(b * addC + oc)) * HWn + y * Wn + px];
                out[oidx] = r;
            }
        }
    }
}

// ---------- postproc ----------
__global__ __launch_bounds__(256) void postK(const float* __restrict__ r18,
                                             float* __restrict__ wh,
                                             float* __restrict__ reg) {
    const int hw = (blockIdx.x & 63) * 256 + threadIdx.x;
    const int b = blockIdx.x >> 6;
    const float* p = r18 + (size_t)(b * 18) * HWn + hw;
    float v[18];
#pragma unroll
    for (int c = 0; c < 18; ++c) v[c] = p[(size_t)c * HWn];
    float s0 = 0.f, s1 = 0.f;
#pragma unroll
    for (int q = 0; q < 9; ++q) { s0 += v[2 * q]; s1 += v[2 * q + 1]; }
    float m0 = s0 * (1.f / 9.f), m1 = s1 * (1.f / 9.f);
    float w0 = 0.f, w1 = 0.f;
#pragma unroll
    for (int q = 0; q < 9; ++q) {
        w0 = fmaxf(w0, fabsf(v[2 * q] + m0));
        w1 = fmaxf(w1, fabsf(v[2 * q + 1] + m1));
    }
    wh[(size_t)(b * 2 + 0) * HWn + hw] = w0;
    wh[(size_t)(b * 2 + 1) * HWn + hw] = w1;
    reg[(size_t)(b * 2 + 0) * HWn + hw] = m0;
    reg[(size_t)(b * 2 + 1) * HWn + hw] = m1;
}

// ---------- host ----------
extern "C" void kernel_launch(void* const* d_in, const int* in_sizes, int n_in,
                              void* d_out, int out_size, void* d_ws, size_t ws_size,
                              hipStream_t stream) {
    const float* x           = (const float*)d_in[0];
    const float* cls_w0      = (const float*)d_in[1];
    const float* cls_b0      = (const float*)d_in[2];
    const float* reg_w0      = (const float*)d_in[3];
    const float* reg_b0      = (const float*)d_in[4];
    const float* cls_w1      = (const float*)d_in[5];
    const float* cls_b1      = (const float*)d_in[6];
    const float* reg_w1      = (const float*)d_in[7];
    const float* reg_b1      = (const float*)d_in[8];
    const float* cls_w2      = (const float*)d_in[9];
    const float* cls_b2      = (const float*)d_in[10];
    const float* reg_w2      = (const float*)d_in[11];
    const float* reg_b2      = (const float*)d_in[12];
    const float* init_conv_w = (const float*)d_in[13];
    const float* init_conv_b = (const float*)d_in[14];
    const float* init_out_w  = (const float*)d_in[15];
    const float* init_out_b  = (const float*)d_in[16];
    const float* dcn_cls_w   = (const float*)d_in[17];
    const float* cls_out_w   = (const float*)d_in[18];
    const float* cls_out_b   = (const float*)d_in[19];
    const float* dcn_ref_w   = (const float*)d_in[20];
    const float* ref_out_w   = (const float*)d_in[21];
    const float* ref_out_b   = (const float*)d_in[22];

    float* out = (float*)d_out;

    char* ws = (char*)d_ws;
    const size_t IMG = (size_t)Bn * HWn * Cn * sizeof(unsigned short);  // 16 MiB
    unsigned short* Xb  = (unsigned short*)ws; ws += IMG;
    unsigned short* T1  = (unsigned short*)ws; ws += IMG;
    unsigned short* T2  = (unsigned short*)ws; ws += IMG;
    unsigned short* CLS = (unsigned short*)ws; ws += IMG;
    unsigned short* PTS = (unsigned short*)ws; ws += IMG;
    float* O27 = (float*)ws; ws += (size_t)Bn * 27 * HWn * sizeof(float);
    float* R18 = (float*)ws; ws += (size_t)Bn * 18 * HWn * sizeof(float);
    const size_t WSZ = (size_t)9 * Cn * Cn;   // 589824 elems per weight
    unsigned short* Wpk = (unsigned short*)ws; ws += 9 * WSZ * sizeof(unsigned short);
    unsigned short* WhAll = (unsigned short*)ws; ws += 160 * Cn * sizeof(unsigned short);
    unsigned short* ZB = (unsigned short*)ws;  ws += 512;

    unsigned short* W_cls0 = Wpk + 0 * WSZ;
    unsigned short* W_cls1 = Wpk + 1 * WSZ;
    unsigned short* W_cls2 = Wpk + 2 * WSZ;
    unsigned short* W_reg0 = Wpk + 3 * WSZ;
    unsigned short* W_reg1 = Wpk + 4 * WSZ;
    unsigned short* W_reg2 = Wpk + 5 * WSZ;
    unsigned short* W_init = Wpk + 6 * WSZ;
    unsigned short* W_dcls = Wpk + 7 * WSZ;
    unsigned short* W_dref = Wpk + 8 * WSZ;
    unsigned short* Wh27 = WhAll;
    unsigned short* Wh80 = WhAll + 32 * Cn;
    unsigned short* Wh18 = WhAll + 128 * Cn;

    const dim3 blk(256);
    const dim3 cgrd(256, 2);
    const dim3 xgrd(512, 8, Bn);

    zeroK<<<1, 128, 0, stream>>>(ZB);
    WPtrs wp;
    wp.p[0] = cls_w0; wp.p[1] = cls_w1; wp.p[2] = cls_w2;
    wp.p[3] = reg_w0; wp.p[4] = reg_w1; wp.p[5] = reg_w2;
    wp.p[6] = init_conv_w; wp.p[7] = dcn_cls_w; wp.p[8] = dcn_ref_w;
    repackAll<<<dim3(2304, 9), blk, 0, stream>>>(wp, Wpk);
    HPtrs hp; hp.w[0] = init_out_w; hp.w[1] = cls_out_w; hp.w[2] = ref_out_w;
    repackHeads<<<160, blk, 0, stream>>>(hp, WhAll);
    xinK<<<xgrd, blk, 0, stream>>>(x, Xb);

    // cls tower
    convGemm<<<cgrd, blk, 0, stream>>>(Xb, W_cls0, cls_b0, ZB, T1);
    convGemm<<<cgrd, blk, 0, stream>>>(T1, W_cls1, cls_b1, ZB, T2);
    convGemm<<<cgrd, blk, 0, stream>>>(T2, W_cls2, cls_b2, ZB, CLS);
    // reg tower
    convGemm<<<cgrd, blk, 0, stream>>>(Xb, W_reg0, reg_b0, ZB, T1);
    convGemm<<<cgrd, blk, 0, stream>>>(T1, W_reg1, reg_b1, ZB, T2);
    convGemm<<<cgrd, blk, 0, stream>>>(T2, W_reg2, reg_b2, ZB, PTS);
    // init head
    convGemm<<<cgrd, blk, 0, stream>>>(PTS, W_init, init_conv_b, ZB, T1);
    headGemm<27, 32, false><<<256, blk, 0, stream>>>(T1, Wh27, init_out_b, O27, nullptr, 0);
    // cls branch
    dcnGemm<true><<<512, dim3(512), 0, stream>>>(CLS, O27, W_dcls, T2);
    headGemm<80, 96, false><<<256, blk, 0, stream>>>(T2, Wh80, cls_out_b, out, nullptr, 0);
    // refine branch
    dcnGemm<false><<<512, dim3(512), 0, stream>>>(PTS, O27, W_dref, T1);
    headGemm<18, 32, true><<<256, blk, 0, stream>>>(T1, Wh18, ref_out_b, R18, O27, 27);

    postK<<<128, blk, 0, stream>>>(R18,
                                   out + (size_t)Bn * NCn * HWn,
                                   out + (size_t)Bn * NCn * HWn + (size_t)Bn * 2 * HWn);
}

// Round 5
// 584.262 us; speedup vs baseline: 18.2220x; 1.0465x over previous
//
#include <hip/hip_runtime.h>

#define Bn 2
#define Cn 256
#define Hn 128
#define Wn 128
#define HWn 16384
#define NCn 80

typedef __attribute__((ext_vector_type(4))) float f32x4;
typedef __attribute__((ext_vector_type(8))) short bf16x8;

__device__ __forceinline__ float blo(unsigned u) {
    union { unsigned u; float f; } x; x.u = u << 16; return x.f;
}
__device__ __forceinline__ float bhi(unsigned u) {
    union { unsigned u; float f; } x; x.u = u & 0xffff0000u; return x.f;
}
__device__ __forceinline__ unsigned short f2bf(float f) {
    union { float f; unsigned u; } x; x.f = f;
    unsigned u = x.u + 0x7fffu + ((x.u >> 16) & 1u);   // RNE
    return (unsigned short)(u >> 16);
}

// async global->LDS, 16B per lane, wave-uniform LDS base + lane*16
#define GLOAD16(gp, lp) __builtin_amdgcn_global_load_lds( \
    (__attribute__((address_space(1))) unsigned int*)(gp), \
    (__attribute__((address_space(3))) unsigned int*)(lp), 16, 0, 0)

// ---------- zero scratch ----------
__global__ void zeroK(unsigned short* z) { z[threadIdx.x] = 0; }

// ---------- x (NCHW f32) -> NHWC bf16 ----------
__global__ __launch_bounds__(256) void xinK(const float* __restrict__ x,
                                            unsigned short* __restrict__ o) {
    __shared__ float tb[32][33];
    const int b = blockIdx.z;
    const int hw0 = blockIdx.x * 32, c0 = blockIdx.y * 32;
    const int tx = threadIdx.x & 31, ty = threadIdx.x >> 5;
    const float* ip = x + ((size_t)(b * Cn + c0)) * HWn + hw0;
#pragma unroll
    for (int r = 0; r < 4; ++r) tb[ty + 8 * r][tx] = ip[(size_t)(ty + 8 * r) * HWn + tx];
    __syncthreads();
    unsigned short* op = o + ((size_t)(b * HWn + hw0)) * Cn + c0;
#pragma unroll
    for (int r = 0; r < 4; ++r) op[(size_t)(ty + 8 * r) * Cn + tx] = f2bf(tb[tx][ty + 8 * r]);
}

// ---------- fused weight repack (coalesced): 9x (O,I,3,3) f32 -> [w][k][oc][ic] bf16 ----------
// one thread = one (w, oc, ic): reads 9 contiguous floats, writes 9 k-planes.
struct WPtrs { const float* p[9]; };
__global__ __launch_bounds__(256) void repackAll(WPtrs wsrc, unsigned short* __restrict__ dst) {
    const int t = blockIdx.x * 256 + threadIdx.x;     // < 589824
    const int widx = t >> 16;                          // 0..8
    const int r = t & 65535;                           // oc*256+ic
    const float* s = wsrc.p[widx] + (size_t)r * 9;
    float v[9];
#pragma unroll
    for (int k = 0; k < 9; ++k) v[k] = s[k];
    unsigned short* d = dst + (size_t)widx * 589824 + r;
#pragma unroll
    for (int k = 0; k < 9; ++k) d[(size_t)k * 65536] = f2bf(v[k]);
}

// ---------- fused head repack: rows [0,32)=w27, [32,128)=w80, [128,160)=w18 ----------
struct HPtrs { const float* w[3]; };
__global__ __launch_bounds__(256) void repackHeads(HPtrs hs, unsigned short* __restrict__ dst) {
    const int t = blockIdx.x * 256 + threadIdx.x;     // < 160*256
    const int ic = t & 255, row = t >> 8;
    int which, oc, OC;
    if (row < 32)       { which = 0; oc = row;       OC = 27; }
    else if (row < 128) { which = 1; oc = row - 32;  OC = 80; }
    else                { which = 2; oc = row - 128; OC = 18; }
    dst[t] = (oc < OC) ? f2bf(hs.w[which][(size_t)oc * Cn + ic]) : (unsigned short)0;
}

// ---------- batched implicit-GEMM 3x3 conv, NHWC bf16 -> NHWC bf16, bias+ReLU ----------
// grid (256, 2, NJ), block 256 (4 waves, 2 oc x 2 px), tile 128oc x 128px, BK=64
struct CJobs {
    const unsigned short* feat[2];
    const unsigned short* W[2];
    const float* bias[2];
    unsigned short* out[2];
};
__global__ __launch_bounds__(256, 2) void convGemm(CJobs jobs,
                                                   const unsigned short* __restrict__ zb) {
    const int jz = blockIdx.z;
    const unsigned short* feat = jobs.feat[jz];
    const unsigned short* Wp = jobs.W[jz];
    const float* bias = jobs.bias[jz];
    unsigned short* outp = jobs.out[jz];

    __shared__ __align__(16) unsigned short lA[2][8192];   // weights [oc][ic]
    __shared__ __align__(16) unsigned short lB[2][8192];   // feat [px][ic]
    const int tid = threadIdx.x;
    const int l = tid & 63, w = tid >> 6;
    const int w_oc = w & 1, w_px = w >> 1;
    const int ry = (blockIdx.x & 7) * 32 + (blockIdx.x >> 3);   // XCD-chunked rows
    const int b = ry >> 7, y = ry & 127;
    const int oc0 = blockIdx.y * 128;
    const int lr = l & 15, lg = l >> 4;

    int rI[4], cI[4], dI[4];
#pragma unroll
    for (int i = 0; i < 4; ++i) {
        int ps = (i * 4 + w) * 64 + l;            // physical 16B slot
        rI[i] = ps >> 3;
        cI[i] = ((ps & 7) ^ (rI[i] & 7)) * 8;     // pre-swizzled source chunk
        dI[i] = (i * 4 + w) * 512;                // wave-uniform LDS elem base
    }

    f32x4 acc[4][4];
#pragma unroll
    for (int i = 0; i < 4; ++i)
#pragma unroll
        for (int j = 0; j < 4; ++j) acc[i][j] = (f32x4){0.f, 0.f, 0.f, 0.f};

    auto stage = [&](int p, int bufIdx) {
        const int k = p >> 2, c0 = (p & 3) * 64;
        const int dy = k / 3 - 1, dx = k % 3 - 1;
        const int yy = y + dy;
        const bool vy = (unsigned)yy < (unsigned)Hn;
        const size_t fbase = ((size_t)(b * Hn + yy)) * Wn;
        const unsigned short* wk = Wp + (size_t)k * 65536 + (size_t)oc0 * Cn + c0;
        unsigned short* la = lA[bufIdx];
        unsigned short* lb = lB[bufIdx];
#pragma unroll
        for (int i = 0; i < 4; ++i)
            GLOAD16(wk + rI[i] * Cn + cI[i], la + dI[i]);
#pragma unroll
        for (int i = 0; i < 4; ++i) {
            const int pxs = rI[i] + dx;
            const unsigned short* g = (vy && (unsigned)pxs < (unsigned)Wn)
                ? feat + ((fbase + pxs) * Cn + c0 + cI[i])
                : zb;
            GLOAD16(g, lb + dI[i]);
        }
    };

    stage(0, 0);
    __syncthreads();

#pragma unroll 1
    for (int p = 0; p < 36; ++p) {
        const int cur = p & 1;
        if (p < 35) stage(p + 1, cur ^ 1);      // async, overlaps MFMA below
        const unsigned short* la = lA[cur];
        const unsigned short* lb = lB[cur];
#pragma unroll
        for (int h = 0; h < 2; ++h) {
            const int ch = h * 4 + lg;
            bf16x8 av[4], bv[4];
#pragma unroll
            for (int fm = 0; fm < 4; ++fm) {
                const int row = w_oc * 64 + fm * 16 + lr;
                av[fm] = *(const bf16x8*)&la[row * 64 + ((ch ^ (row & 7)) * 8)];
            }
#pragma unroll
            for (int fn = 0; fn < 4; ++fn) {
                const int row = w_px * 64 + fn * 16 + lr;
                bv[fn] = *(const bf16x8*)&lb[row * 64 + ((ch ^ (row & 7)) * 8)];
            }
#pragma unroll
            for (int fm = 0; fm < 4; ++fm)
#pragma unroll
                for (int fn = 0; fn < 4; ++fn)
                    acc[fm][fn] = __builtin_amdgcn_mfma_f32_16x16x32_bf16(
                        av[fm], bv[fn], acc[fm][fn], 0, 0, 0);
        }
        __syncthreads();
    }

#pragma unroll
    for (int fm = 0; fm < 4; ++fm) {
        const int ocb = oc0 + w_oc * 64 + fm * 16 + lg * 4;
        const float b0 = bias[ocb], b1 = bias[ocb + 1], b2 = bias[ocb + 2], b3 = bias[ocb + 3];
#pragma unroll
        for (int fn = 0; fn < 4; ++fn) {
            const int px = w_px * 64 + fn * 16 + lr;
            f32x4 v = acc[fm][fn];
            unsigned u0 = (unsigned)f2bf(fmaxf(v[0] + b0, 0.f)) | ((unsigned)f2bf(fmaxf(v[1] + b1, 0.f)) << 16);
            unsigned u1 = (unsigned)f2bf(fmaxf(v[2] + b2, 0.f)) | ((unsigned)f2bf(fmaxf(v[3] + b3, 0.f)) << 16);
            uint2 st; st.x = u0; st.y = u1;
            *(uint2*)&outp[((size_t)ry * Wn + px) * Cn + ocb] = st;
        }
    }
}

// ---------- deformable conv as sampled implicit GEMM, T14 async-split ----------
// grid (512), block 512 (8 waves, 4 oc x 2 px), tile 256oc x 64px, BK=64, ReLU out
// corner loads for phase p+1 issued BEFORE MFMA(p); interp+ds_write after.
template <bool HASMASK>
__global__ __launch_bounds__(512, 4) void dcnGemm(const unsigned short* __restrict__ feat, // NHWC bf16
                                                  const float* __restrict__ o27,           // NCHW f32
                                                  const unsigned short* __restrict__ Wp,   // [k][oc][ic] bf16
                                                  unsigned short* __restrict__ out) {
    __shared__ __align__(16) unsigned short lA[2][16384];   // 256oc x 64ch
    __shared__ __align__(16) unsigned short lB[2][4096];    // 64px x 64ch
    const int tid = threadIdx.x;
    const int l = tid & 63, w = tid >> 6;
    const int w_oc = w & 3, w_px = w >> 2;
    const int g = (blockIdx.x & 7) * 64 + (blockIdx.x >> 3);  // XCD-chunked
    const int ry = g >> 1, st = g & 1;
    const int b = ry >> 7, y = ry & 127;
    const int x0 = st * 64;
    const int lr = l & 15, lg = l >> 4;

    int rIA[4], cIA[4], dIA[4];
#pragma unroll
    for (int i = 0; i < 4; ++i) {
        int ps = (i * 8 + w) * 64 + l;            // 2048 slots (256 rows x 8)
        rIA[i] = ps >> 3;
        cIA[i] = ((ps & 7) ^ (rIA[i] & 7)) * 8;
        dIA[i] = (i * 8 + w) * 512;
    }

    const int sp = tid >> 3;          // sampled px 0..63
    const int pc = tid & 7;           // chunk 0..7
    const int xg = x0 + sp;
    const int wslot = sp * 64 + ((pc ^ (sp & 7)) * 8);   // swizzled LDS write slot

    const float* ob = o27 + (size_t)b * 27 * HWn + y * Wn + xg;
    const unsigned short* fb = feat + (size_t)b * HWn * Cn;

    f32x4 acc[4][2];
#pragma unroll
    for (int i = 0; i < 4; ++i)
#pragma unroll
        for (int j = 0; j < 2; ++j) acc[i][j] = (f32x4){0.f, 0.f, 0.f, 0.f};

    int ci0, ci1, ci2, ci3;
    float cw0, cw1, cw2, cw3;

    auto sampParams = [&](int k) {
        const float offy = ob[(size_t)(2 * k) * HWn];
        const float offx = ob[(size_t)(2 * k + 1) * HWn];
        const float m = HASMASK ? ob[(size_t)(18 + k) * HWn] : 1.f;
        const float py = (float)(y + k / 3 - 1) + offy;
        const float px = (float)(xg + k % 3 - 1) + offx;
        const float y0f = floorf(py), x0f = floorf(px);
        const float wy1 = py - y0f, wx1 = px - x0f;
        const int iy0 = (int)y0f, ix0 = (int)x0f;
        const int iy1 = iy0 + 1, ix1 = ix0 + 1;
        const bool vy0 = (unsigned)iy0 < (unsigned)Hn, vy1 = (unsigned)iy1 < (unsigned)Hn;
        const bool vx0 = (unsigned)ix0 < (unsigned)Wn, vx1 = (unsigned)ix1 < (unsigned)Wn;
        const int yc0 = min(max(iy0, 0), Hn - 1), yc1 = min(max(iy1, 0), Hn - 1);
        const int xc0 = min(max(ix0, 0), Wn - 1), xc1 = min(max(ix1, 0), Wn - 1);
        cw0 = (vy0 && vx0) ? (1.f - wy1) * (1.f - wx1) * m : 0.f;
        cw1 = (vy0 && vx1) ? (1.f - wy1) * wx1 * m : 0.f;
        cw2 = (vy1 && vx0) ? wy1 * (1.f - wx1) * m : 0.f;
        cw3 = (vy1 && vx1) ? wy1 * wx1 * m : 0.f;
        ci0 = (yc0 * Wn + xc0) * Cn;
        ci1 = (yc0 * Wn + xc1) * Cn;
        ci2 = (yc1 * Wn + xc0) * Cn;
        ci3 = (yc1 * Wn + xc1) * Cn;
    };

    int4 q0, q1, q2, q3;
    auto cornerLoads = [&](int p) {
        const int cb = (p & 3) * 64 + pc * 8;
        q0 = *(const int4*)(fb + ci0 + cb);
        q1 = *(const int4*)(fb + ci1 + cb);
        q2 = *(const int4*)(fb + ci2 + cb);
        q3 = *(const int4*)(fb + ci3 + cb);
    };
    auto stageA = [&](int p, int bufIdx) {
        const int k = p >> 2, c0 = (p & 3) * 64;
        const unsigned short* wk = Wp + (size_t)k * 65536 + c0;
        unsigned short* la = lA[bufIdx];
#pragma unroll
        for (int i = 0; i < 4; ++i)
            GLOAD16(wk + rIA[i] * Cn + cIA[i], la + dIA[i]);
    };
    auto interpWrite = [&](int bufIdx) {
        unsigned u[4];
#pragma unroll
        for (int jj = 0; jj < 4; ++jj) {
            const unsigned a0 = ((const unsigned*)&q0)[jj];
            const unsigned a1 = ((const unsigned*)&q1)[jj];
            const unsigned a2 = ((const unsigned*)&q2)[jj];
            const unsigned a3 = ((const unsigned*)&q3)[jj];
            float e0 = cw0 * blo(a0) + cw1 * blo(a1) + cw2 * blo(a2) + cw3 * blo(a3);
            float e1 = cw0 * bhi(a0) + cw1 * bhi(a1) + cw2 * bhi(a2) + cw3 * bhi(a3);
            u[jj] = (unsigned)f2bf(e0) | ((unsigned)f2bf(e1) << 16);
        }
        int4 pk; pk.x = u[0]; pk.y = u[1]; pk.z = u[2]; pk.w = u[3];
        *(int4*)&lB[bufIdx][wslot] = pk;
    };

    // prologue: phase 0 fully staged
    sampParams(0);
    stageA(0, 0);
    cornerLoads(0);
    interpWrite(0);
    __syncthreads();

#pragma unroll 1
    for (int p = 0; p < 36; ++p) {
        const int cur = p & 1;
        if (p < 35) {
            if (((p + 1) & 3) == 0) sampParams((p + 1) >> 2);
            stageA(p + 1, cur ^ 1);       // async -> lA[nxt]
            cornerLoads(p + 1);           // into regs, waited after MFMA
        }
        const unsigned short* la = lA[cur];
        const unsigned short* lb = lB[cur];
#pragma unroll
        for (int h = 0; h < 2; ++h) {
            const int ch = h * 4 + lg;
            bf16x8 av[4], bv[2];
#pragma unroll
            for (int fm = 0; fm < 4; ++fm) {
                const int row = w_oc * 64 + fm * 16 + lr;
                av[fm] = *(const bf16x8*)&la[row * 64 + ((ch ^ (row & 7)) * 8)];
            }
#pragma unroll
            for (int fn = 0; fn < 2; ++fn) {
                const int row = w_px * 32 + fn * 16 + lr;
                bv[fn] = *(const bf16x8*)&lb[row * 64 + ((ch ^ (row & 7)) * 8)];
            }
#pragma unroll
            for (int fm = 0; fm < 4; ++fm)
#pragma unroll
                for (int fn = 0; fn < 2; ++fn)
                    acc[fm][fn] = __builtin_amdgcn_mfma_f32_16x16x32_bf16(
                        av[fm], bv[fn], acc[fm][fn], 0, 0, 0);
        }
        if (p < 35) interpWrite(cur ^ 1);   // wait corners + interp AFTER MFMA
        __syncthreads();
    }

#pragma unroll
    for (int fm = 0; fm < 4; ++fm) {
        const int ocb = w_oc * 64 + fm * 16 + lg * 4;
#pragma unroll
        for (int fn = 0; fn < 2; ++fn) {
            const int px = x0 + w_px * 32 + fn * 16 + lr;
            f32x4 v = acc[fm][fn];
            unsigned u0 = (unsigned)f2bf(fmaxf(v[0], 0.f)) | ((unsigned)f2bf(fmaxf(v[1], 0.f)) << 16);
            unsigned u1 = (unsigned)f2bf(fmaxf(v[2], 0.f)) | ((unsigned)f2bf(fmaxf(v[3], 0.f)) << 16);
            uint2 stv; stv.x = u0; stv.y = u1;
            *(uint2*)&out[((size_t)ry * Wn + px) * Cn + ocb] = stv;
        }
    }
}

// ---------- MFMA 1x1 head: NHWC bf16 in, NCHW f32 out (+bias, +optional add) ----------
// grid (256), block 256 (4 waves over px), tile PMoc x 128px, BK=64
// POST=true: instead of writing OC-channel map, fuse postK (wh/reg outputs).
template <int OC, int PM, bool ADD, bool POST>
__global__ __launch_bounds__(256, 2) void headGemm(const unsigned short* __restrict__ feat,
                                                   const unsigned short* __restrict__ Wp,   // [PM][256] bf16
                                                   const float* __restrict__ bias,
                                                   float* __restrict__ out,      // POST: wh base
                                                   const float* __restrict__ add,
                                                   int addC,
                                                   float* __restrict__ reg) {
    constexpr int MF = PM / 16;
    constexpr int NA = PM * 8 / 256;
    __shared__ __align__(16) unsigned short lA[PM * 64];
    __shared__ __align__(16) unsigned short lB[128 * 64];
    __shared__ float lR[POST ? 18 : 1][POST ? 128 : 1];
    const int tid = threadIdx.x;
    const int l = tid & 63, w = tid >> 6;
    const int ry = (blockIdx.x & 7) * 32 + (blockIdx.x >> 3);
    const int b = ry >> 7, y = ry & 127;
    const int lr = l & 15, lg = l >> 4;

    int rIA[NA], cIA[NA], dIA[NA];
#pragma unroll
    for (int i = 0; i < NA; ++i) {
        int ps = (i * 4 + w) * 64 + l;
        rIA[i] = ps >> 3;
        cIA[i] = ((ps & 7) ^ (rIA[i] & 7)) * 8;
        dIA[i] = (i * 4 + w) * 512;
    }
    int rIB[4], cIB[4], dIB[4];
#pragma unroll
    for (int i = 0; i < 4; ++i) {
        int ps = (i * 4 + w) * 64 + l;
        rIB[i] = ps >> 3;
        cIB[i] = ((ps & 7) ^ (rIB[i] & 7)) * 8;
        dIB[i] = (i * 4 + w) * 512;
    }

    f32x4 acc[MF][2];
#pragma unroll
    for (int i = 0; i < MF; ++i)
#pragma unroll
        for (int j = 0; j < 2; ++j) acc[i][j] = (f32x4){0.f, 0.f, 0.f, 0.f};

    const unsigned short* frow = feat + ((size_t)ry * Wn) * Cn;

#pragma unroll 1
    for (int cc = 0; cc < 4; ++cc) {
        const int c0 = cc * 64;
#pragma unroll
        for (int i = 0; i < NA; ++i)
            GLOAD16(Wp + (size_t)rIA[i] * Cn + c0 + cIA[i], &lA[dIA[i]]);
#pragma unroll
        for (int i = 0; i < 4; ++i)
            GLOAD16(frow + (size_t)rIB[i] * Cn + c0 + cIB[i], &lB[dIB[i]]);
        __syncthreads();
#pragma unroll
        for (int h = 0; h < 2; ++h) {
            const int ch = h * 4 + lg;
            bf16x8 av[MF], bv[2];
#pragma unroll
            for (int fm = 0; fm < MF; ++fm) {
                const int row = fm * 16 + lr;
                av[fm] = *(const bf16x8*)&lA[row * 64 + ((ch ^ (row & 7)) * 8)];
            }
#pragma unroll
            for (int fn = 0; fn < 2; ++fn) {
                const int row = w * 32 + fn * 16 + lr;
                bv[fn] = *(const bf16x8*)&lB[row * 64 + ((ch ^ (row & 7)) * 8)];
            }
#pragma unroll
            for (int fm = 0; fm < MF; ++fm)
#pragma unroll
                for (int fn = 0; fn < 2; ++fn)
                    acc[fm][fn] = __builtin_amdgcn_mfma_f32_16x16x32_bf16(
                        av[fm], bv[fn], acc[fm][fn], 0, 0, 0);
        }
        __syncthreads();
    }

    if (!POST) {
#pragma unroll
        for (int fm = 0; fm < MF; ++fm) {
            const int ocb = fm * 16 + lg * 4;
            if (ocb >= OC) break;
#pragma unroll
            for (int j = 0; j < 4; ++j) {
                const int oc = ocb + j;
                if (oc >= OC) break;
                const float bs = bias[oc];
#pragma unroll
                for (int fn = 0; fn < 2; ++fn) {
                    const int px = w * 32 + fn * 16 + lr;
                    float r = acc[fm][fn][j] + bs;
                    if (ADD) r += add[((size_t)(b * addC + oc)) * HWn + y * Wn + px];
                    out[((size_t)(b * OC + oc)) * HWn + y * Wn + px] = r;
                }
            }
        }
    } else {
        // stage r18 into LDS, then postproc (wh/reg) in-kernel
#pragma unroll
        for (int fm = 0; fm < MF; ++fm) {
            const int ocb = fm * 16 + lg * 4;
#pragma unroll
            for (int j = 0; j < 4; ++j) {
                const int oc = ocb + j;
                if (oc < 18) {
                    const float bs = bias[oc];
#pragma unroll
                    for (int fn = 0; fn < 2; ++fn) {
                        const int px = w * 32 + fn * 16 + lr;
                        float r = acc[fm][fn][j] + bs
                                + add[((size_t)(b * addC + oc)) * HWn + y * Wn + px];
                        lR[oc][px] = r;
                    }
                }
            }
        }
        __syncthreads();
        if (tid < 128) {
            const int px = tid;
            float v[18];
#pragma unroll
            for (int c = 0; c < 18; ++c) v[c] = lR[c][px];
            float s0 = 0.f, s1 = 0.f;
#pragma unroll
            for (int q = 0; q < 9; ++q) { s0 += v[2 * q]; s1 += v[2 * q + 1]; }
            float m0 = s0 * (1.f / 9.f), m1 = s1 * (1.f / 9.f);
            float w0 = 0.f, w1 = 0.f;
#pragma unroll
            for (int q = 0; q < 9; ++q) {
                w0 = fmaxf(w0, fabsf(v[2 * q] + m0));
                w1 = fmaxf(w1, fabsf(v[2 * q + 1] + m1));
            }
            const size_t hw = (size_t)y * Wn + px;
            out[(size_t)(b * 2 + 0) * HWn + hw] = w0;
            out[(size_t)(b * 2 + 1) * HWn + hw] = w1;
            reg[(size_t)(b * 2 + 0) * HWn + hw] = m0;
            reg[(size_t)(b * 2 + 1) * HWn + hw] = m1;
        }
    }
}

// ---------- host ----------
extern "C" void kernel_launch(void* const* d_in, const int* in_sizes, int n_in,
                              void* d_out, int out_size, void* d_ws, size_t ws_size,
                              hipStream_t stream) {
    const float* x           = (const float*)d_in[0];
    const float* cls_w0      = (const float*)d_in[1];
    const float* cls_b0      = (const float*)d_in[2];
    const float* reg_w0      = (const float*)d_in[3];
    const float* reg_b0      = (const float*)d_in[4];
    const float* cls_w1      = (const float*)d_in[5];
    const float* cls_b1      = (const float*)d_in[6];
    const float* reg_w1      = (const float*)d_in[7];
    const float* reg_b1      = (const float*)d_in[8];
    const float* cls_w2      = (const float*)d_in[9];
    const float* cls_b2      = (const float*)d_in[10];
    const float* reg_w2      = (const float*)d_in[11];
    const float* reg_b2      = (const float*)d_in[12];
    const float* init_conv_w = (const float*)d_in[13];
    const float* init_conv_b = (const float*)d_in[14];
    const float* init_out_w  = (const float*)d_in[15];
    const float* init_out_b  = (const float*)d_in[16];
    const float* dcn_cls_w   = (const float*)d_in[17];
    const float* cls_out_w   = (const float*)d_in[18];
    const float* cls_out_b   = (const float*)d_in[19];
    const float* dcn_ref_w   = (const float*)d_in[20];
    const float* ref_out_w   = (const float*)d_in[21];
    const float* ref_out_b   = (const float*)d_in[22];

    float* out = (float*)d_out;

    char* ws = (char*)d_ws;
    const size_t IMG = (size_t)Bn * HWn * Cn * sizeof(unsigned short);  // 16 MiB
    unsigned short* B0 = (unsigned short*)ws; ws += IMG;
    unsigned short* B1 = (unsigned short*)ws; ws += IMG;
    unsigned short* B2 = (unsigned short*)ws; ws += IMG;
    unsigned short* B3 = (unsigned short*)ws; ws += IMG;
    float* O27 = (float*)ws; ws += (size_t)Bn * 27 * HWn * sizeof(float);
    const size_t WSZ = (size_t)9 * Cn * Cn;   // 589824 elems per weight
    unsigned short* Wpk = (unsigned short*)ws; ws += 9 * WSZ * sizeof(unsigned short);
    unsigned short* WhAll = (unsigned short*)ws; ws += 160 * Cn * sizeof(unsigned short);
    unsigned short* ZB = (unsigned short*)ws;  ws += 512;

    unsigned short* W_cls0 = Wpk + 0 * WSZ;
    unsigned short* W_cls1 = Wpk + 1 * WSZ;
    unsigned short* W_cls2 = Wpk + 2 * WSZ;
    unsigned short* W_reg0 = Wpk + 3 * WSZ;
    unsigned short* W_reg1 = Wpk + 4 * WSZ;
    unsigned short* W_reg2 = Wpk + 5 * WSZ;
    unsigned short* W_init = Wpk + 6 * WSZ;
    unsigned short* W_dcls = Wpk + 7 * WSZ;
    unsigned short* W_dref = Wpk + 8 * WSZ;
    unsigned short* Wh27 = WhAll;
    unsigned short* Wh80 = WhAll + 32 * Cn;
    unsigned short* Wh18 = WhAll + 128 * Cn;

    const dim3 blk(256);
    const dim3 xgrd(512, 8, Bn);

    zeroK<<<1, 128, 0, stream>>>(ZB);
    WPtrs wp;
    wp.p[0] = cls_w0; wp.p[1] = cls_w1; wp.p[2] = cls_w2;
    wp.p[3] = reg_w0; wp.p[4] = reg_w1; wp.p[5] = reg_w2;
    wp.p[6] = init_conv_w; wp.p[7] = dcn_cls_w; wp.p[8] = dcn_ref_w;
    repackAll<<<2304, blk, 0, stream>>>(wp, Wpk);
    HPtrs hp; hp.w[0] = init_out_w; hp.w[1] = cls_out_w; hp.w[2] = ref_out_w;
    repackHeads<<<160, blk, 0, stream>>>(hp, WhAll);
    xinK<<<xgrd, blk, 0, stream>>>(x, B0);

    // buffer plan:
    // L0: B0 -> {B1 (cls), B2 (reg)}
    // L1: {B1->B3, B2->B0}
    // L2: {B3->B1 (CLS), B0->B2 (PTS)}
    // init conv: B2 -> B3 ; head27: B3 -> O27
    // dcn cls: B1 -> B0 ; head80 -> out
    // dcn ref: B2 -> B3 ; head18(+post) -> out tail
    CJobs j;
    // L0 (shared input)
    j.feat[0] = B0; j.W[0] = W_cls0; j.bias[0] = cls_b0; j.out[0] = B1;
    j.feat[1] = B0; j.W[1] = W_reg0; j.bias[1] = reg_b0; j.out[1] = B2;
    convGemm<<<dim3(256, 2, 2), blk, 0, stream>>>(j, ZB);
    // L1
    j.feat[0] = B1; j.W[0] = W_cls1; j.bias[0] = cls_b1; j.out[0] = B3;
    j.feat[1] = B2; j.W[1] = W_reg1; j.bias[1] = reg_b1; j.out[1] = B0;
    convGemm<<<dim3(256, 2, 2), blk, 0, stream>>>(j, ZB);
    // L2
    j.feat[0] = B3; j.W[0] = W_cls2; j.bias[0] = cls_b2; j.out[0] = B1;   // CLS
    j.feat[1] = B0; j.W[1] = W_reg2; j.bias[1] = reg_b2; j.out[1] = B2;   // PTS
    convGemm<<<dim3(256, 2, 2), blk, 0, stream>>>(j, ZB);
    // init conv
    j.feat[0] = B2; j.W[0] = W_init; j.bias[0] = init_conv_b; j.out[0] = B3;
    j.feat[1] = B2; j.W[1] = W_init; j.bias[1] = init_conv_b; j.out[1] = B3;
    convGemm<<<dim3(256, 2, 1), blk, 0, stream>>>(j, ZB);
    headGemm<27, 32, false, false><<<256, blk, 0, stream>>>(B3, Wh27, init_out_b, O27, nullptr, 0, nullptr);
    // cls branch
    dcnGemm<true><<<512, dim3(512), 0, stream>>>(B1, O27, W_dcls, B0);
    headGemm<80, 96, false, false><<<256, blk, 0, stream>>>(B0, Wh80, cls_out_b, out, nullptr, 0, nullptr);
    // refine branch (head18 fuses postproc: writes wh + reg directly)
    dcnGemm<false><<<512, dim3(512), 0, stream>>>(B2, O27, W_dref, B3);
    headGemm<18, 32, true, true><<<256, blk, 0, stream>>>(
        B3, Wh18, ref_out_b,
        out + (size_t)Bn * NCn * HWn,          // wh
        O27, 27,
        out + (size_t)Bn * NCn * HWn + (size_t)Bn * 2 * HWn);  // reg
}